// Round 6
// baseline (158.726 us; speedup 1.0000x reference)
//
#include <hip/hip_runtime.h>
#include <math.h>

#define C_CH 256
#define NPOS 4096              // 64*64 spatial positions
#define PAD_W 66
#define PAD_HW (PAD_W*PAD_W)   // 4356
#define GSLICE 32              // gram position-axis slices (128 pos each)
#define CHUNK 8                // diagonal steps per score block

typedef __bf16 bf16x8 __attribute__((ext_vector_type(8)));
typedef float  f32x4  __attribute__((ext_vector_type(4)));

__device__ __forceinline__ int reflect_idx(int p) {
    int s = p - 1;
    if (s < 0) s = -s;
    if (s > 63) s = 126 - s;
    return s;
}

__device__ __forceinline__ unsigned short f2bf(float x) {
    unsigned int u = __float_as_uint(x);
    unsigned int r = u + 0x7fffu + ((u >> 16) & 1u);
    return (unsigned short)(r >> 16);
}

// async global->LDS, 16B per lane; LDS dest = wave-uniform base + lane*16
__device__ __forceinline__ void gload16(const void* g, void* l) {
    __builtin_amdgcn_global_load_lds(
        (const __attribute__((address_space(1))) unsigned int*)g,
        (__attribute__((address_space(3))) unsigned int*)l, 16, 0, 0);
}

// ---------------- transpose + hi/lo bf16 split: [c][64x64] -> [pos4356][c] ----------------
__global__ void __launch_bounds__(256)
split_kernel(const float* __restrict__ content, const float* __restrict__ style,
             unsigned short* __restrict__ cTH, unsigned short* __restrict__ cTL,
             unsigned short* __restrict__ sTH, unsigned short* __restrict__ sTL) {
    __shared__ float tile[64][65];
    const float* src = blockIdx.z ? style : content;
    unsigned short* oH = blockIdx.z ? sTH : cTH;
    unsigned short* oL = blockIdx.z ? sTL : cTL;
    int t = threadIdx.x;
    int p0 = blockIdx.x * 64, c0 = blockIdx.y * 64;
    int posl = t & 63;
    int p = p0 + posl; int pc = p < PAD_HW ? p : PAD_HW - 1;
    int py = pc / PAD_W, px = pc - py * PAD_W;
    int rawIdx = reflect_idx(py) * 64 + reflect_idx(px);
    #pragma unroll
    for (int r = 0; r < 16; ++r) {
        int cl = (t >> 6) + r * 4;
        tile[posl][cl] = src[(size_t)(c0 + cl) * NPOS + rawIdx];
    }
    __syncthreads();
    int cl2 = t & 63;
    #pragma unroll
    for (int r = 0; r < 16; ++r) {
        int pl = (t >> 6) + r * 4;
        int pg = p0 + pl;
        if (pg < PAD_HW) {
            float x = tile[pl][cl2];
            unsigned short h = f2bf(x);
            float hf = __uint_as_float((unsigned int)h << 16);
            unsigned short l = f2bf(x - hf);
            oH[(size_t)pg * C_CH + c0 + cl2] = h;
            oL[(size_t)pg * C_CH + c0 + cl2] = l;
        }
    }
}

// ---------------- per-raw-position style squared sums (8 channel-group partials) ----------------
__global__ void __launch_bounds__(256)
ssp_kernel(const float* __restrict__ style, float* __restrict__ SSp) {
    int pos = blockIdx.x * 256 + threadIdx.x;   // grid.x = 16
    int cg = blockIdx.y;                        // 0..7
    float s = 0.f;
    for (int c = cg * 32; c < cg * 32 + 32; ++c) {
        float v = style[(size_t)c * NPOS + pos];
        s += v * v;
    }
    SSp[cg * NPOS + pos] = s;
}

// ---------------- style patch inverse norms ----------------
__global__ void rs_kernel(const float* __restrict__ SSp, float* __restrict__ rs) {
    int j = blockIdx.x * blockDim.x + threadIdx.x;
    if (j >= NPOS) return;
    int yj = j >> 6, xj = j & 63;
    float s = 0.f;
    #pragma unroll
    for (int kh = 0; kh < 3; ++kh) {
        int ry = reflect_idx(yj + kh);
        #pragma unroll
        for (int kw = 0; kw < 3; ++kw) {
            int p = ry * 64 + reflect_idx(xj + kw);
            #pragma unroll
            for (int part = 0; part < 8; ++part)
                s += SSp[part * NPOS + p];
        }
    }
    rs[j] = 1.0f / sqrtf(s);
}

// ---------------- split-bf16 MFMA E-GEMM ----------------
// R5-proven structure (dbuf + gload16 + counted vmcnt + setprio). R5 lesson:
// sync-structure changes are null at this depth; the 43us plateau was cache
// thrash (FETCH 62MB vs 17.8MB inputs) from the 76MB E stream. Fix is host-
// side L3 blocking (NG=2): E slice 39MB + inputs 18MB fit L3, so stage loads
// hit L3 and E write+re-read stays on-die. Kernel unchanged.
__global__ void __launch_bounds__(256)
egemm_mfma(const unsigned short* __restrict__ AH, const unsigned short* __restrict__ AL,
           const unsigned short* __restrict__ BH, const unsigned short* __restrict__ BL,
           float* __restrict__ E, int colBaseQ, int colLim, int Ncols, int gx, int nwg) {
    __shared__ short sm[32768];                 // 2 buffers x 4 arrays x [128][32] bf16 = 64KB

    int orig = blockIdx.x;
    int q = nwg >> 3, r = nwg & 7;
    int xcd = orig & 7, rank = orig >> 3;
    int L = (xcd < r ? xcd * (q + 1) : r * (q + 1) + (xcd - r) * q) + rank;
    int by = L / gx, bx = L - by * gx;

    int t = threadIdx.x;
    int lane = t & 63, wv = t >> 6;
    int wr = wv >> 1, wc = wv & 1;
    int bm = by * 128, bn = bx * 128;
    int rowLoc = wv * 16 + (lane >> 2);          // 0..63 within half-tile
    int kc2 = (((lane & 3) ^ ((lane >> 3) & 3))) << 3;   // swizzled src k-offset (elems)
    int krd = (((lane >> 4) ^ ((lane >> 1) & 3))) << 3;  // swizzled frag-read k-offset

    int rA0 = bm + rowLoc;            if (rA0 > PAD_HW - 1) rA0 = PAD_HW - 1;
    int rA1 = bm + 64 + rowLoc;       if (rA1 > PAD_HW - 1) rA1 = PAD_HW - 1;
    int rB0 = colBaseQ + bn + rowLoc;       if (rB0 > PAD_HW - 1) rB0 = PAD_HW - 1;
    int rB1 = colBaseQ + bn + 64 + rowLoc;  if (rB1 > PAD_HW - 1) rB1 = PAD_HW - 1;

    const unsigned short* gA0 = AH + (size_t)rA0 * C_CH + kc2;
    const unsigned short* gA1 = AH + (size_t)rA1 * C_CH + kc2;
    const unsigned short* gA0l = AL + (size_t)rA0 * C_CH + kc2;
    const unsigned short* gA1l = AL + (size_t)rA1 * C_CH + kc2;
    const unsigned short* gB0 = BH + (size_t)rB0 * C_CH + kc2;
    const unsigned short* gB1 = BH + (size_t)rB1 * C_CH + kc2;
    const unsigned short* gB0l = BL + (size_t)rB0 * C_CH + kc2;
    const unsigned short* gB1l = BL + (size_t)rB1 * C_CH + kc2;
    int lb = wv * 512;                // shorts: wave-uniform LDS base

    auto STAGE = [&](short* base, int koff) {
        gload16(gA0  + koff, base + lb);
        gload16(gA1  + koff, base + 2048 + lb);
        gload16(gA0l + koff, base + 4096 + lb);
        gload16(gA1l + koff, base + 6144 + lb);
        gload16(gB0  + koff, base + 8192 + lb);
        gload16(gB1  + koff, base + 10240 + lb);
        gload16(gB0l + koff, base + 12288 + lb);
        gload16(gB1l + koff, base + 14336 + lb);
    };

    f32x4 acc[4][4];
    #pragma unroll
    for (int mt = 0; mt < 4; ++mt)
        #pragma unroll
        for (int nt = 0; nt < 4; ++nt)
            acc[mt][nt] = (f32x4){0.f, 0.f, 0.f, 0.f};

    STAGE(sm, 0);                                // tile 0 in flight (8 loads)

    #pragma unroll
    for (int ks = 0; ks < 8; ++ks) {
        short* cb = sm + (ks & 1) * 16384;
        if (ks < 7) {
            STAGE(sm + ((ks + 1) & 1) * 16384, (ks + 1) * 32);   // +8 in flight
            asm volatile("s_waitcnt vmcnt(8)" ::: "memory");     // tile ks landed
        } else {
            asm volatile("s_waitcnt vmcnt(0)" ::: "memory");     // last tile
        }
        __builtin_amdgcn_s_barrier();            // all waves see tile ks
        __builtin_amdgcn_sched_barrier(0);

        short* sAH = cb;
        short* sAL = cb + 4096;
        short* sBH = cb + 8192;
        short* sBL = cb + 12288;
        bf16x8 aH[4], aL[4], bH[4], bL[4];
        #pragma unroll
        for (int mt = 0; mt < 4; ++mt) {
            int off = (wr * 64 + mt * 16 + (lane & 15)) * 32 + krd;
            aH[mt] = *(const bf16x8*)(sAH + off);
            aL[mt] = *(const bf16x8*)(sAL + off);
        }
        #pragma unroll
        for (int nt = 0; nt < 4; ++nt) {
            int off = (wc * 64 + nt * 16 + (lane & 15)) * 32 + krd;
            bH[nt] = *(const bf16x8*)(sBH + off);
            bL[nt] = *(const bf16x8*)(sBL + off);
        }
        __builtin_amdgcn_s_setprio(1);
        #pragma unroll
        for (int mt = 0; mt < 4; ++mt)
            #pragma unroll
            for (int nt = 0; nt < 4; ++nt) {
                f32x4 c = acc[mt][nt];
                c = __builtin_amdgcn_mfma_f32_16x16x32_bf16(aH[mt], bH[nt], c, 0, 0, 0);
                c = __builtin_amdgcn_mfma_f32_16x16x32_bf16(aH[mt], bL[nt], c, 0, 0, 0);
                c = __builtin_amdgcn_mfma_f32_16x16x32_bf16(aL[mt], bH[nt], c, 0, 0, 0);
                acc[mt][nt] = c;
            }
        __builtin_amdgcn_s_setprio(0);

        asm volatile("s_waitcnt lgkmcnt(0)" ::: "memory");   // own ds_reads done
        __builtin_amdgcn_s_barrier();            // all reads done -> overwrite safe
        __builtin_amdgcn_sched_barrier(0);
    }

    // ---- direct store: padded Ncols makes each 16-lane run a full 64B line ----
    #pragma unroll
    for (int mt = 0; mt < 4; ++mt) {
        int row0 = bm + wr * 64 + mt * 16 + (lane >> 4) * 4;
        #pragma unroll
        for (int nt = 0; nt < 4; ++nt) {
            int col = bn + wc * 64 + nt * 16 + (lane & 15);
            if (col < colLim) {
                #pragma unroll
                for (int r2 = 0; r2 < 4; ++r2) {
                    int row = row0 + r2;
                    if (row < PAD_HW)
                        E[(size_t)row * Ncols + col] = acc[mt][nt][r2];
                }
            }
        }
    }
}

// ---------------- fused 9-tap score + normalize + argmax ----------------
// Diagonal-persistent blocks + register-window taps (stride-68 LDS, b128 reads).
__global__ void __launch_bounds__(256)
score_argmax(const float* __restrict__ E, const float* __restrict__ rs,
             float* __restrict__ pval, int* __restrict__ pidx,
             int g, int R, int Ncols) {
    __shared__ float T[3 * 66 * 68];   // 3 strip buffers, stride 68

    int bid = blockIdx.x;
    int d = bid % R;                   // diagonal
    int c = bid / R;                   // chunk
    int s0 = c * CHUNK;
    int t = threadIdx.x;
    int xi = t & 63, s2 = t >> 6, xj0 = s2 * 16;

    int u0 = t / 66, v0 = t - u0 * 66; // walk base for e = t + 256*i

    bool valid = false;
    float r[18];

    for (int s = s0; s < s0 + CHUNK; ++s) {
        int yjl = (s + d) & (R - 1);

        if (!valid) {                  // warmup / post-wrap: load 3 strips
            __syncthreads();
            for (int kh = 0; kh < 3; ++kh) {
                float* Tb = T + ((s + kh) % 3) * 4488;
                const float* Eb = E + (size_t)((s + kh) * 66) * Ncols + (yjl + kh) * 66;
                int u = u0, v = v0;
                #pragma unroll
                for (int i = 0; i < 17; ++i) {
                    Tb[u * 68 + v] = Eb[(size_t)u * Ncols + v];
                    v += 58; u += 3; if (v >= 66) { v -= 66; ++u; }
                }
                if (t < 4) Tb[65 * 68 + 62 + t] = Eb[(size_t)65 * Ncols + 62 + t];
            }
            __syncthreads();
            valid = true;
        }

        // prefetch next step's new strip into regs (issue before compute)
        int yjl_next = (s + 1 + d) & (R - 1);
        bool pf = (s + 1 < s0 + CHUNK) && (yjl_next == yjl + 1);
        if (pf) {
            const float* Eb = E + (size_t)((s + 3) * 66) * Ncols + (yjl + 3) * 66;
            int u = u0, v = v0;
            #pragma unroll
            for (int i = 0; i < 17; ++i) {
                r[i] = Eb[(size_t)u * Ncols + v];
                v += 58; u += 3; if (v >= 66) { v -= 66; ++u; }
            }
            if (t < 4) r[17] = Eb[(size_t)65 * Ncols + 62 + t];
        }

        // compute 9-tap scores for this (yi=s, yjl): register row-windows
        float sc[16];
        #pragma unroll
        for (int q2 = 0; q2 < 16; ++q2) sc[q2] = 0.f;
        #pragma unroll
        for (int kh = 0; kh < 3; ++kh) {
            const float* Tk = T + ((s + kh) % 3) * 4488;
            #pragma unroll
            for (int kw = 0; kw < 3; ++kw) {
                const float* rp = Tk + (xi + kw) * 68 + xj0;
                float rr[18];
                *(float4*)&rr[0]  = *(const float4*)&rp[0];
                *(float4*)&rr[4]  = *(const float4*)&rp[4];
                *(float4*)&rr[8]  = *(const float4*)&rp[8];
                *(float4*)&rr[12] = *(const float4*)&rp[12];
                if (kw > 0) *(float2*)&rr[16] = *(const float2*)&rp[16];
                #pragma unroll
                for (int q2 = 0; q2 < 16; ++q2) sc[q2] += rr[kw + q2];
            }
        }

        // normalize + local argmax over this thread's 16 xj
        int jbase = ((g * R + yjl) << 6) + xj0;
        float bv = -INFINITY; int bj = 0;
        #pragma unroll
        for (int q2 = 0; q2 < 16; ++q2) {
            float v = sc[q2] * rs[jbase + q2];
            if (v > bv) { bv = v; bj = jbase + q2; }
        }
        int part = (g * R + yjl) * 4 + s2;
        pval[(size_t)part * NPOS + (s << 6) + xi] = bv;
        pidx[(size_t)part * NPOS + (s << 6) + xi] = bj;

        if (pf) {                      // drain prefetch into freed buffer
            __syncthreads();
            float* Tb = T + ((s + 3) % 3) * 4488;
            int u = u0, v = v0;
            #pragma unroll
            for (int i = 0; i < 17; ++i) {
                Tb[u * 68 + v] = r[i];
                v += 58; u += 3; if (v >= 66) { v -= 66; ++u; }
            }
            if (t < 4) Tb[65 * 68 + 62 + t] = r[17];
            __syncthreads();
        } else {
            valid = false;
        }
    }
}

// ---------------- final argmax across 256 partial slots (parallel) ----------------
__global__ void __launch_bounds__(256)
argmax_reduce_kernel(const float* __restrict__ pval,
                     const int* __restrict__ pidx,
                     int* __restrict__ idx) {
    __shared__ float sv[4][64];
    __shared__ int   sj[4][64];
    int il = threadIdx.x & 63;
    int sg = threadIdx.x >> 6;
    int i = blockIdx.x * 64 + il;
    float bv = -INFINITY; int bj = 0x7fffffff;
    #pragma unroll 4
    for (int k = 0; k < 64; ++k) {
        int sl = sg * 64 + k;
        float v = pval[(size_t)sl * NPOS + i];
        int   j = pidx[(size_t)sl * NPOS + i];
        if (v > bv || (v == bv && j < bj)) { bv = v; bj = j; }
    }
    sv[sg][il] = bv; sj[sg][il] = bj;
    __syncthreads();
    if (sg == 0) {
        #pragma unroll
        for (int u = 1; u < 4; ++u) {
            float ov = sv[u][il]; int oj = sj[u][il];
            if (ov > bv || (ov == bv && oj < bj)) { bv = ov; bj = oj; }
        }
        idx[i] = bj;
    }
}

// ---------------- build masked matrices as split-bf16 H/L [c][4096] ----------------
__global__ void __launch_bounds__(256)
build_xy_kernel(const float* __restrict__ input_fm,
                const float* __restrict__ style,
                const float* __restrict__ mask,
                const int* __restrict__ idx,
                unsigned short* __restrict__ XmH, unsigned short* __restrict__ XmL,
                unsigned short* __restrict__ YmH, unsigned short* __restrict__ YmL) {
    int e4 = blockIdx.x * 256 + threadIdx.x;    // grid 1024: C_CH*NPOS/4
    int c = e4 >> 10;
    int i0 = (e4 & 1023) << 2;
    int base = (c << 12) + i0;
    float4 inv = *(const float4*)&input_fm[base];
    float4 mv  = *(const float4*)&mask[i0];
    const float* sc = style + ((size_t)c << 12);
    float x[4], y[4];
    x[0] = inv.x * mv.x; x[1] = inv.y * mv.y; x[2] = inv.z * mv.z; x[3] = inv.w * mv.w;
    y[0] = sc[idx[i0 + 0]] * mv.x;
    y[1] = sc[idx[i0 + 1]] * mv.y;
    y[2] = sc[idx[i0 + 2]] * mv.z;
    y[3] = sc[idx[i0 + 3]] * mv.w;
    ushort4 xh, xl, yh, yl;
    #pragma unroll
    for (int j = 0; j < 4; ++j) {
        unsigned short h = f2bf(x[j]);
        float hf = __uint_as_float((unsigned int)h << 16);
        ((unsigned short*)&xh)[j] = h;
        ((unsigned short*)&xl)[j] = f2bf(x[j] - hf);
        unsigned short h2 = f2bf(y[j]);
        float hf2 = __uint_as_float((unsigned int)h2 << 16);
        ((unsigned short*)&yh)[j] = h2;
        ((unsigned short*)&yl)[j] = f2bf(y[j] - hf2);
    }
    *(ushort4*)&XmH[base] = xh;
    *(ushort4*)&XmL[base] = xl;
    *(ushort4*)&YmH[base] = yh;
    *(ushort4*)&YmL[base] = yl;
}

// ---------------- MFMA dual-gram diff: 64x64 tiles x 32 pos-slices ----------------
// R2-proven dbuf structure + counted-vmcnt discipline (same as egemm).
// Upper-triangle tiles only; compact coalesced output via LDS restage.
__global__ void __launch_bounds__(256)
gram_mfma(const unsigned short* __restrict__ XH, const unsigned short* __restrict__ XL,
          const unsigned short* __restrict__ YH, const unsigned short* __restrict__ YL,
          float* __restrict__ Dpart) {
    __shared__ short sm[32768];   // 2 buf x 8 arrays x [64][32] bf16 = 64 KB
    const int PI[10] = {0,0,0,0,1,1,1,2,2,3};
    const int PJ[10] = {0,1,2,3,1,2,3,2,3,3};
    int pr = blockIdx.x, sl = blockIdx.y;
    int ti = PI[pr], tj = PJ[pr];
    int c0 = ti * 64, d0 = tj * 64;
    int t = threadIdx.x, lane = t & 63, wv = t >> 6;
    int wr = wv >> 1, wc = wv & 1;
    int rowLoc = wv * 16 + (lane >> 2);                  // 0..63
    int kc2 = (((lane & 3) ^ ((lane >> 3) & 3))) << 3;
    int krd = (((lane >> 4) ^ ((lane >> 1) & 3))) << 3;
    int posBase = sl * 128 + kc2;

    const unsigned short* g0 = XH + (size_t)(c0 + rowLoc) * NPOS + posBase;
    const unsigned short* g1 = XL + (size_t)(c0 + rowLoc) * NPOS + posBase;
    const unsigned short* g2 = XH + (size_t)(d0 + rowLoc) * NPOS + posBase;
    const unsigned short* g3 = XL + (size_t)(d0 + rowLoc) * NPOS + posBase;
    const unsigned short* g4 = YH + (size_t)(c0 + rowLoc) * NPOS + posBase;
    const unsigned short* g5 = YL + (size_t)(c0 + rowLoc) * NPOS + posBase;
    const unsigned short* g6 = YH + (size_t)(d0 + rowLoc) * NPOS + posBase;
    const unsigned short* g7 = YL + (size_t)(d0 + rowLoc) * NPOS + posBase;
    int lb = wv * 512;

    auto STAGE = [&](short* base, int koff) {
        gload16(g0 + koff, base + lb);
        gload16(g1 + koff, base + 2048 + lb);
        gload16(g2 + koff, base + 4096 + lb);
        gload16(g3 + koff, base + 6144 + lb);
        gload16(g4 + koff, base + 8192 + lb);
        gload16(g5 + koff, base + 10240 + lb);
        gload16(g6 + koff, base + 12288 + lb);
        gload16(g7 + koff, base + 14336 + lb);
    };

    f32x4 aX[2][2], aY[2][2];
    #pragma unroll
    for (int mt = 0; mt < 2; ++mt)
        #pragma unroll
        for (int nt = 0; nt < 2; ++nt) {
            aX[mt][nt] = (f32x4){0.f, 0.f, 0.f, 0.f};
            aY[mt][nt] = (f32x4){0.f, 0.f, 0.f, 0.f};
        }

    STAGE(sm, 0);

    #pragma unroll
    for (int ks = 0; ks < 4; ++ks) {
        short* cb = sm + (ks & 1) * 16384;
        if (ks < 3) {
            STAGE(sm + ((ks + 1) & 1) * 16384, (ks + 1) * 32);
            asm volatile("s_waitcnt vmcnt(8)" ::: "memory");
        } else {
            asm volatile("s_waitcnt vmcnt(0)" ::: "memory");
        }
        __builtin_amdgcn_s_barrier();
        __builtin_amdgcn_sched_barrier(0);

        bf16x8 xcH[2], xcL[2], xdH[2], xdL[2], ycH[2], ycL[2], ydH[2], ydL[2];
        #pragma unroll
        for (int mt = 0; mt < 2; ++mt) {
            int off = (wr * 32 + mt * 16 + (lane & 15)) * 32 + krd;
            xcH[mt] = *(const bf16x8*)(cb + off);
            xcL[mt] = *(const bf16x8*)(cb + 2048 + off);
            ycH[mt] = *(const bf16x8*)(cb + 8192 + off);
            ycL[mt] = *(const bf16x8*)(cb + 10240 + off);
        }
        #pragma unroll
        for (int nt = 0; nt < 2; ++nt) {
            int off = (wc * 32 + nt * 16 + (lane & 15)) * 32 + krd;
            xdH[nt] = *(const bf16x8*)(cb + 4096 + off);
            xdL[nt] = *(const bf16x8*)(cb + 6144 + off);
            ydH[nt] = *(const bf16x8*)(cb + 12288 + off);
            ydL[nt] = *(const bf16x8*)(cb + 14336 + off);
        }
        __builtin_amdgcn_s_setprio(1);
        #pragma unroll
        for (int mt = 0; mt < 2; ++mt)
            #pragma unroll
            for (int nt = 0; nt < 2; ++nt) {
                f32x4 cx = aX[mt][nt];
                cx = __builtin_amdgcn_mfma_f32_16x16x32_bf16(xcH[mt], xdH[nt], cx, 0, 0, 0);
                cx = __builtin_amdgcn_mfma_f32_16x16x32_bf16(xcH[mt], xdL[nt], cx, 0, 0, 0);
                cx = __builtin_amdgcn_mfma_f32_16x16x32_bf16(xcL[mt], xdH[nt], cx, 0, 0, 0);
                aX[mt][nt] = cx;
                f32x4 cy = aY[mt][nt];
                cy = __builtin_amdgcn_mfma_f32_16x16x32_bf16(ycH[mt], ydH[nt], cy, 0, 0, 0);
                cy = __builtin_amdgcn_mfma_f32_16x16x32_bf16(ycH[mt], ydL[nt], cy, 0, 0, 0);
                cy = __builtin_amdgcn_mfma_f32_16x16x32_bf16(ycL[mt], ydH[nt], cy, 0, 0, 0);
                aY[mt][nt] = cy;
            }
        __builtin_amdgcn_s_setprio(0);

        asm volatile("s_waitcnt lgkmcnt(0)" ::: "memory");
        __builtin_amdgcn_s_barrier();
        __builtin_amdgcn_sched_barrier(0);
    }

    // ---- coalesced epilogue: 64x64 diff tile via LDS (stride 68), float4 out ----
    float* fs = (float*)sm;                      // 64*68*4 = 17.4KB < 64KB
    #pragma unroll
    for (int mt = 0; mt < 2; ++mt) {
        int rl = wr * 32 + mt * 16 + ((lane >> 4) << 2);
        #pragma unroll
        for (int nt = 0; nt < 2; ++nt) {
            int cl = wc * 32 + nt * 16 + (lane & 15);
            #pragma unroll
            for (int r2 = 0; r2 < 4; ++r2)
                fs[(rl + r2) * 68 + cl] = aX[mt][nt][r2] - aY[mt][nt][r2];
        }
    }
    __syncthreads();
    float* Db = Dpart + ((size_t)sl * 10 + pr) * 4096;
    int rr0 = t >> 4;              // 0..15
    int cc0 = (t & 15) << 2;       // 0..60
    #pragma unroll
    for (int i = 0; i < 4; ++i) {
        int rr = rr0 + (i << 4);
        *(float4*)&Db[rr * 64 + cc0] = *(const float4*)&fs[rr * 68 + cc0];
    }
}

// ---------------- final loss (mask-sum fused; upper-tile iteration, off-diag x2) ----------------
__global__ void __launch_bounds__(256)
loss_kernel(const float* __restrict__ Dpart, const float* __restrict__ mask,
            float* __restrict__ out) {
    const int PI[10] = {0,0,0,0,1,1,1,2,2,3};
    const int PJ[10] = {0,1,2,3,1,2,3,2,3,3};
    __shared__ float red[4];
    int tid = threadIdx.x;

    // redundant per-block mask sum (16KB read; replaces separate msum kernel)
    float ms = 0.f;
    for (int i = tid; i < NPOS; i += 256) ms += mask[i];
    #pragma unroll
    for (int o = 32; o >= 1; o >>= 1) ms += __shfl_down(ms, o, 64);
    if ((tid & 63) == 0) red[tid >> 6] = ms;
    __syncthreads();
    float msum = 256.0f * (red[0] + red[1] + red[2] + red[3]);
    __syncthreads();                    // red[] reused below

    int e2 = blockIdx.x * 256 + tid;    // grid 160: 10 tiles x 4096
    int tt = e2 >> 12;                  // uniform within block
    int ei = e2 & 4095;
    float d = 0.f;
    #pragma unroll
    for (int s = 0; s < GSLICE; ++s)
        d += Dpart[(size_t)(s * 10 + tt) * 4096 + ei];
    float inv = 1.0f / msum;
    float v = d * inv;
    float w = (PI[tt] != PJ[tt]) ? 2.0f : 1.0f;
    float ls = w * v * v;
    #pragma unroll
    for (int o = 32; o >= 1; o >>= 1) ls += __shfl_down(ls, o, 64);
    if ((tid & 63) == 0) red[tid >> 6] = ls;
    __syncthreads();
    if (tid == 0)
        atomicAdd(out, (red[0] + red[1] + red[2] + red[3]) * (100.0f / 65536.0f));
}

extern "C" void kernel_launch(void* const* d_in, const int* in_sizes, int n_in,
                              void* d_out, int out_size, void* d_ws, size_t ws_size,
                              hipStream_t stream) {
    (void)in_sizes; (void)n_in; (void)out_size;
    const float* content = (const float*)d_in[0];
    const float* style   = (const float*)d_in[1];
    const float* input   = (const float*)d_in[2];
    const float* mask    = (const float*)d_in[3];
    float* out = (float*)d_out;

    auto alignup = [](size_t b) { return (b + 255) & ~size_t(255); };

    size_t szT   = alignup((size_t)PAD_HW * C_CH * 2);
    size_t szSS  = alignup((size_t)8 * NPOS * 4);
    size_t szRS  = alignup((size_t)NPOS * 4);
    size_t szPV  = alignup((size_t)256 * NPOS * 4);
    size_t szIdx = alignup((size_t)NPOS * 4);
    size_t szXYb = alignup((size_t)C_CH * NPOS * 2);    // bf16 H/L arrays
    size_t szDp  = alignup((size_t)GSLICE * 10 * 4096 * 4);
    size_t fixed = 4 * szT + szSS + szRS + 2 * szPV + szIdx + 4 * szXYb + szDp;

    // E row stride padded to a multiple of 16 floats (64B) -> full-line stores
    auto padcols = [](int c) { return (c + 15) & ~15; };

    auto needE = [&](int NG) {
        size_t Nc = (size_t)padcols((64 / NG + 2) * PAD_W);
        return fixed + alignup((size_t)PAD_HW * Nc * 4) + 4096;
    };
    // L3 blocking (R5 lesson): NG=2 keeps the E slice at ~39MB so slice+inputs
    // (~57MB) stay resident in the 256MB Infinity Cache -- E write+re-read and
    // A/B stage re-reads never round-trip HBM. NG=1 (76MB E, streaming) caused
    // FETCH 3.5x inputs. NG starts at 2 deliberately.
    int NG = 8;
    if      (ws_size >= needE(2)) NG = 2;
    else if (ws_size >= needE(4)) NG = 4;
    int R = 64 / NG;
    int colLim = (R + 2) * PAD_W;          // real columns
    int Ncols = padcols(colLim);           // padded row stride

    char* ws = (char*)d_ws;
    size_t off = 0;
    auto alloc = [&](size_t bytes) { void* p = ws + off; off += alignup(bytes); return p; };

    unsigned short* cTH = (unsigned short*)alloc((size_t)PAD_HW * C_CH * 2);
    unsigned short* cTL = (unsigned short*)alloc((size_t)PAD_HW * C_CH * 2);
    unsigned short* sTH = (unsigned short*)alloc((size_t)PAD_HW * C_CH * 2);
    unsigned short* sTL = (unsigned short*)alloc((size_t)PAD_HW * C_CH * 2);
    float* SSp   = (float*)alloc((size_t)8 * NPOS * 4);
    float* rs    = (float*)alloc((size_t)NPOS * 4);
    float* pval  = (float*)alloc((size_t)256 * NPOS * 4);
    int*   pidx  = (int*)  alloc((size_t)256 * NPOS * 4);
    int*   idx   = (int*)  alloc((size_t)NPOS * 4);
    unsigned short* XmH = (unsigned short*)alloc((size_t)C_CH * NPOS * 2);
    unsigned short* XmL = (unsigned short*)alloc((size_t)C_CH * NPOS * 2);
    unsigned short* YmH = (unsigned short*)alloc((size_t)C_CH * NPOS * 2);
    unsigned short* YmL = (unsigned short*)alloc((size_t)C_CH * NPOS * 2);
    float* Dpart = (float*)alloc((size_t)GSLICE * 10 * 4096 * 4);
    float* E     = (float*)alloc((size_t)PAD_HW * Ncols * 4);

    hipMemsetAsync(d_out, 0, sizeof(float), stream);

    split_kernel<<<dim3(69, 4, 2), 256, 0, stream>>>(content, style, cTH, cTL, sTH, sTL);
    ssp_kernel<<<dim3(16, 8), 256, 0, stream>>>(style, SSp);
    rs_kernel<<<16, 256, 0, stream>>>(SSp, rs);

    int gx = (colLim + 127) / 128;
    int gy = (PAD_HW + 127) / 128;
    int nwg = gx * gy;
    for (int g = 0; g < NG; ++g) {
        int colBaseQ = g * R * PAD_W;
        egemm_mfma<<<nwg, 256, 0, stream>>>(cTH, cTL, sTH, sTL, E, colBaseQ, colLim, Ncols, gx, nwg);
        score_argmax<<<R * (64 / CHUNK), 256, 0, stream>>>(E, rs, pval, pidx, g, R, Ncols);
    }
    argmax_reduce_kernel<<<64, 256, 0, stream>>>(pval, pidx, idx);
    build_xy_kernel<<<1024, 256, 0, stream>>>(input, style, mask, idx, XmH, XmL, YmH, YmL);
    gram_mfma<<<dim3(10, GSLICE), 256, 0, stream>>>(XmH, XmL, YmH, YmL, Dpart);
    loss_kernel<<<160, 256, 0, stream>>>(Dpart, mask, out);
}

// Round 7
// 141.517 us; speedup vs baseline: 1.1216x; 1.1216x over previous
//
#include <hip/hip_runtime.h>
#include <math.h>

#define C_CH 256
#define NPOS 4096              // 64*64 spatial positions
#define PAD_W 66
#define PAD_HW (PAD_W*PAD_W)   // 4356
#define GSLICE 32              // gram position-axis slices (128 pos each)
#define CHUNK 8                // diagonal steps per score block

typedef __bf16 bf16x8 __attribute__((ext_vector_type(8)));
typedef float  f32x4  __attribute__((ext_vector_type(4)));

__device__ __forceinline__ int reflect_idx(int p) {
    int s = p - 1;
    if (s < 0) s = -s;
    if (s > 63) s = 126 - s;
    return s;
}

__device__ __forceinline__ unsigned short f2bf(float x) {
    unsigned int u = __float_as_uint(x);
    unsigned int r = u + 0x7fffu + ((u >> 16) & 1u);
    return (unsigned short)(r >> 16);
}

// async global->LDS, 16B per lane; LDS dest = wave-uniform base + lane*16
__device__ __forceinline__ void gload16(const void* g, void* l) {
    __builtin_amdgcn_global_load_lds(
        (const __attribute__((address_space(1))) unsigned int*)g,
        (__attribute__((address_space(3))) unsigned int*)l, 16, 0, 0);
}

// ---------------- transpose + hi/lo bf16 split: [c][64x64] -> [pos4356][c] ----------------
__global__ void __launch_bounds__(256)
split_kernel(const float* __restrict__ content, const float* __restrict__ style,
             unsigned short* __restrict__ cTH, unsigned short* __restrict__ cTL,
             unsigned short* __restrict__ sTH, unsigned short* __restrict__ sTL) {
    __shared__ float tile[64][65];
    const float* src = blockIdx.z ? style : content;
    unsigned short* oH = blockIdx.z ? sTH : cTH;
    unsigned short* oL = blockIdx.z ? sTL : cTL;
    int t = threadIdx.x;
    int p0 = blockIdx.x * 64, c0 = blockIdx.y * 64;
    int posl = t & 63;
    int p = p0 + posl; int pc = p < PAD_HW ? p : PAD_HW - 1;
    int py = pc / PAD_W, px = pc - py * PAD_W;
    int rawIdx = reflect_idx(py) * 64 + reflect_idx(px);
    #pragma unroll
    for (int r = 0; r < 16; ++r) {
        int cl = (t >> 6) + r * 4;
        tile[posl][cl] = src[(size_t)(c0 + cl) * NPOS + rawIdx];
    }
    __syncthreads();
    int cl2 = t & 63;
    #pragma unroll
    for (int r = 0; r < 16; ++r) {
        int pl = (t >> 6) + r * 4;
        int pg = p0 + pl;
        if (pg < PAD_HW) {
            float x = tile[pl][cl2];
            unsigned short h = f2bf(x);
            float hf = __uint_as_float((unsigned int)h << 16);
            unsigned short l = f2bf(x - hf);
            oH[(size_t)pg * C_CH + c0 + cl2] = h;
            oL[(size_t)pg * C_CH + c0 + cl2] = l;
        }
    }
}

// ---------------- per-raw-position style squared sums (8 channel-group partials) ----------------
__global__ void __launch_bounds__(256)
ssp_kernel(const float* __restrict__ style, float* __restrict__ SSp) {
    int pos = blockIdx.x * 256 + threadIdx.x;   // grid.x = 16
    int cg = blockIdx.y;                        // 0..7
    float s = 0.f;
    for (int c = cg * 32; c < cg * 32 + 32; ++c) {
        float v = style[(size_t)c * NPOS + pos];
        s += v * v;
    }
    SSp[cg * NPOS + pos] = s;
}

// ---------------- style patch inverse norms ----------------
__global__ void rs_kernel(const float* __restrict__ SSp, float* __restrict__ rs) {
    int j = blockIdx.x * blockDim.x + threadIdx.x;
    if (j >= NPOS) return;
    int yj = j >> 6, xj = j & 63;
    float s = 0.f;
    #pragma unroll
    for (int kh = 0; kh < 3; ++kh) {
        int ry = reflect_idx(yj + kh);
        #pragma unroll
        for (int kw = 0; kw < 3; ++kw) {
            int p = ry * 64 + reflect_idx(xj + kw);
            #pragma unroll
            for (int part = 0; part < 8; ++part)
                s += SSp[part * NPOS + p];
        }
    }
    rs[j] = 1.0f / sqrtf(s);
}

// ---------------- split-bf16 MFMA E-GEMM: 8-wave blocks ----------------
// R6 lesson: NG=2 L3-blocking regressed (launch serialization) -> NG=1.
// Plateau diagnosis: 256-thr + 64KB LDS = 2 waves/SIMD -- no latency-hiding
// pool. This round: 512 threads, SAME 128x128 tile + 64KB dbuf. Per-wave work
// halves (acc[4][2], 24 MFMA/step, 4 stage loads), 16 waves/CU = 4/SIMD.
// Staging: wave wv stages half-array wv (4 x gload16, rows i*16+(lane>>2));
// per-16-row write pattern identical to the proven 4-wave version, so the
// kc2/krd swizzle pair carries over unchanged. Counted vmcnt(4) discipline.
__global__ void __launch_bounds__(512, 4)
egemm_mfma(const unsigned short* __restrict__ AH, const unsigned short* __restrict__ AL,
           const unsigned short* __restrict__ BH, const unsigned short* __restrict__ BL,
           float* __restrict__ E, int colBaseQ, int colLim, int Ncols, int gx, int nwg) {
    __shared__ short sm[32768];                 // 2 buffers x 4 arrays x [128][32] bf16 = 64KB

    int orig = blockIdx.x;
    int q = nwg >> 3, r = nwg & 7;
    int xcd = orig & 7, rank = orig >> 3;
    int L = (xcd < r ? xcd * (q + 1) : r * (q + 1) + (xcd - r) * q) + rank;
    int by = L / gx, bx = L - by * gx;

    int t = threadIdx.x;
    int lane = t & 63, wv = t >> 6;              // 8 waves
    int wr = wv >> 2, wc = wv & 3;               // wave tile: 64 rows x 32 cols
    int bm = by * 128, bn = bx * 128;
    int rowLoc = lane >> 2;                      // 0..15 within a 16-row block
    int kc2 = (((lane & 3) ^ ((lane >> 3) & 3))) << 3;   // swizzled src k-offset (elems)
    int krd = (((lane >> 4) ^ ((lane >> 1) & 3))) << 3;  // swizzled frag-read k-offset

    // staging role: wave wv owns half-array wv: {A0H,A1H,A0L,A1L,B0H,B1H,B0L,B1L}
    const unsigned short* mats[4] = {AH, AL, BH, BL};
    const unsigned short* M = mats[wv >> 1];
    int rbase = ((wv >> 1) >= 2 ? colBaseQ + bn : bm) + (wv & 1) * 64;
    const unsigned short* gp[4];
    #pragma unroll
    for (int i = 0; i < 4; ++i) {
        int rr = rbase + i * 16 + rowLoc;
        if (rr > PAD_HW - 1) rr = PAD_HW - 1;
        gp[i] = M + (size_t)rr * C_CH + kc2;
    }
    int ldst = wv * 2048;                        // shorts: wave's half-array base

    auto STAGE = [&](short* base, int koff) {
        #pragma unroll
        for (int i = 0; i < 4; ++i)
            gload16(gp[i] + koff, base + ldst + i * 512);
    };

    f32x4 acc[4][2];
    #pragma unroll
    for (int mt = 0; mt < 4; ++mt)
        #pragma unroll
        for (int nt = 0; nt < 2; ++nt)
            acc[mt][nt] = (f32x4){0.f, 0.f, 0.f, 0.f};

    STAGE(sm, 0);                                // tile 0: 4 loads in flight/wave

    #pragma unroll
    for (int ks = 0; ks < 8; ++ks) {
        short* cb = sm + (ks & 1) * 16384;
        if (ks < 7) {
            STAGE(sm + ((ks + 1) & 1) * 16384, (ks + 1) * 32);   // +4 in flight
            asm volatile("s_waitcnt vmcnt(4)" ::: "memory");     // tile ks landed
        } else {
            asm volatile("s_waitcnt vmcnt(0)" ::: "memory");
        }
        __builtin_amdgcn_s_barrier();
        __builtin_amdgcn_sched_barrier(0);

        short* sAH = cb;
        short* sAL = cb + 4096;
        short* sBH = cb + 8192;
        short* sBL = cb + 12288;
        bf16x8 aH[4], aL[4], bH[2], bL[2];
        #pragma unroll
        for (int mt = 0; mt < 4; ++mt) {
            int off = (wr * 64 + mt * 16 + (lane & 15)) * 32 + krd;
            aH[mt] = *(const bf16x8*)(sAH + off);
            aL[mt] = *(const bf16x8*)(sAL + off);
        }
        #pragma unroll
        for (int nt = 0; nt < 2; ++nt) {
            int off = (wc * 32 + nt * 16 + (lane & 15)) * 32 + krd;
            bH[nt] = *(const bf16x8*)(sBH + off);
            bL[nt] = *(const bf16x8*)(sBL + off);
        }
        __builtin_amdgcn_s_setprio(1);
        #pragma unroll
        for (int mt = 0; mt < 4; ++mt)
            #pragma unroll
            for (int nt = 0; nt < 2; ++nt) {
                f32x4 c = acc[mt][nt];
                c = __builtin_amdgcn_mfma_f32_16x16x32_bf16(aH[mt], bH[nt], c, 0, 0, 0);
                c = __builtin_amdgcn_mfma_f32_16x16x32_bf16(aH[mt], bL[nt], c, 0, 0, 0);
                c = __builtin_amdgcn_mfma_f32_16x16x32_bf16(aL[mt], bH[nt], c, 0, 0, 0);
                acc[mt][nt] = c;
            }
        __builtin_amdgcn_s_setprio(0);

        asm volatile("s_waitcnt lgkmcnt(0)" ::: "memory");
        __builtin_amdgcn_s_barrier();
        __builtin_amdgcn_sched_barrier(0);
    }

    // ---- direct store: padded Ncols makes each 16-lane run a full 64B line ----
    #pragma unroll
    for (int mt = 0; mt < 4; ++mt) {
        int row0 = bm + wr * 64 + mt * 16 + (lane >> 4) * 4;
        #pragma unroll
        for (int nt = 0; nt < 2; ++nt) {
            int col = bn + wc * 32 + nt * 16 + (lane & 15);
            if (col < colLim) {
                #pragma unroll
                for (int r2 = 0; r2 < 4; ++r2) {
                    int row = row0 + r2;
                    if (row < PAD_HW)
                        E[(size_t)row * Ncols + col] = acc[mt][nt][r2];
                }
            }
        }
    }
}

// ---------------- fused 9-tap score + normalize + argmax ----------------
// Diagonal-persistent blocks + register-window taps (stride-68 LDS, b128 reads).
__global__ void __launch_bounds__(256)
score_argmax(const float* __restrict__ E, const float* __restrict__ rs,
             float* __restrict__ pval, int* __restrict__ pidx,
             int g, int R, int Ncols) {
    __shared__ float T[3 * 66 * 68];   // 3 strip buffers, stride 68

    int bid = blockIdx.x;
    int d = bid % R;                   // diagonal
    int c = bid / R;                   // chunk
    int s0 = c * CHUNK;
    int t = threadIdx.x;
    int xi = t & 63, s2 = t >> 6, xj0 = s2 * 16;

    int u0 = t / 66, v0 = t - u0 * 66; // walk base for e = t + 256*i

    bool valid = false;
    float r[18];

    for (int s = s0; s < s0 + CHUNK; ++s) {
        int yjl = (s + d) & (R - 1);

        if (!valid) {                  // warmup / post-wrap: load 3 strips
            __syncthreads();
            for (int kh = 0; kh < 3; ++kh) {
                float* Tb = T + ((s + kh) % 3) * 4488;
                const float* Eb = E + (size_t)((s + kh) * 66) * Ncols + (yjl + kh) * 66;
                int u = u0, v = v0;
                #pragma unroll
                for (int i = 0; i < 17; ++i) {
                    Tb[u * 68 + v] = Eb[(size_t)u * Ncols + v];
                    v += 58; u += 3; if (v >= 66) { v -= 66; ++u; }
                }
                if (t < 4) Tb[65 * 68 + 62 + t] = Eb[(size_t)65 * Ncols + 62 + t];
            }
            __syncthreads();
            valid = true;
        }

        // prefetch next step's new strip into regs (issue before compute)
        int yjl_next = (s + 1 + d) & (R - 1);
        bool pf = (s + 1 < s0 + CHUNK) && (yjl_next == yjl + 1);
        if (pf) {
            const float* Eb = E + (size_t)((s + 3) * 66) * Ncols + (yjl + 3) * 66;
            int u = u0, v = v0;
            #pragma unroll
            for (int i = 0; i < 17; ++i) {
                r[i] = Eb[(size_t)u * Ncols + v];
                v += 58; u += 3; if (v >= 66) { v -= 66; ++u; }
            }
            if (t < 4) r[17] = Eb[(size_t)65 * Ncols + 62 + t];
        }

        // compute 9-tap scores for this (yi=s, yjl): register row-windows
        float sc[16];
        #pragma unroll
        for (int q2 = 0; q2 < 16; ++q2) sc[q2] = 0.f;
        #pragma unroll
        for (int kh = 0; kh < 3; ++kh) {
            const float* Tk = T + ((s + kh) % 3) * 4488;
            #pragma unroll
            for (int kw = 0; kw < 3; ++kw) {
                const float* rp = Tk + (xi + kw) * 68 + xj0;
                float rr[18];
                *(float4*)&rr[0]  = *(const float4*)&rp[0];
                *(float4*)&rr[4]  = *(const float4*)&rp[4];
                *(float4*)&rr[8]  = *(const float4*)&rp[8];
                *(float4*)&rr[12] = *(const float4*)&rp[12];
                if (kw > 0) *(float2*)&rr[16] = *(const float2*)&rp[16];
                #pragma unroll
                for (int q2 = 0; q2 < 16; ++q2) sc[q2] += rr[kw + q2];
            }
        }

        // normalize + local argmax over this thread's 16 xj
        int jbase = ((g * R + yjl) << 6) + xj0;
        float bv = -INFINITY; int bj = 0;
        #pragma unroll
        for (int q2 = 0; q2 < 16; ++q2) {
            float v = sc[q2] * rs[jbase + q2];
            if (v > bv) { bv = v; bj = jbase + q2; }
        }
        int part = (g * R + yjl) * 4 + s2;
        pval[(size_t)part * NPOS + (s << 6) + xi] = bv;
        pidx[(size_t)part * NPOS + (s << 6) + xi] = bj;

        if (pf) {                      // drain prefetch into freed buffer
            __syncthreads();
            float* Tb = T + ((s + 3) % 3) * 4488;
            int u = u0, v = v0;
            #pragma unroll
            for (int i = 0; i < 17; ++i) {
                Tb[u * 68 + v] = r[i];
                v += 58; u += 3; if (v >= 66) { v -= 66; ++u; }
            }
            if (t < 4) Tb[65 * 68 + 62 + t] = r[17];
            __syncthreads();
        } else {
            valid = false;
        }
    }
}

// ---------------- final argmax across 256 partial slots (parallel) ----------------
__global__ void __launch_bounds__(256)
argmax_reduce_kernel(const float* __restrict__ pval,
                     const int* __restrict__ pidx,
                     int* __restrict__ idx) {
    __shared__ float sv[4][64];
    __shared__ int   sj[4][64];
    int il = threadIdx.x & 63;
    int sg = threadIdx.x >> 6;
    int i = blockIdx.x * 64 + il;
    float bv = -INFINITY; int bj = 0x7fffffff;
    #pragma unroll 4
    for (int k = 0; k < 64; ++k) {
        int sl = sg * 64 + k;
        float v = pval[(size_t)sl * NPOS + i];
        int   j = pidx[(size_t)sl * NPOS + i];
        if (v > bv || (v == bv && j < bj)) { bv = v; bj = j; }
    }
    sv[sg][il] = bv; sj[sg][il] = bj;
    __syncthreads();
    if (sg == 0) {
        #pragma unroll
        for (int u = 1; u < 4; ++u) {
            float ov = sv[u][il]; int oj = sj[u][il];
            if (ov > bv || (ov == bv && oj < bj)) { bv = ov; bj = oj; }
        }
        idx[i] = bj;
    }
}

// ---------------- build masked matrices as split-bf16 H/L [c][4096] ----------------
__global__ void __launch_bounds__(256)
build_xy_kernel(const float* __restrict__ input_fm,
                const float* __restrict__ style,
                const float* __restrict__ mask,
                const int* __restrict__ idx,
                unsigned short* __restrict__ XmH, unsigned short* __restrict__ XmL,
                unsigned short* __restrict__ YmH, unsigned short* __restrict__ YmL) {
    int e4 = blockIdx.x * 256 + threadIdx.x;    // grid 1024: C_CH*NPOS/4
    int c = e4 >> 10;
    int i0 = (e4 & 1023) << 2;
    int base = (c << 12) + i0;
    float4 inv = *(const float4*)&input_fm[base];
    float4 mv  = *(const float4*)&mask[i0];
    const float* sc = style + ((size_t)c << 12);
    float x[4], y[4];
    x[0] = inv.x * mv.x; x[1] = inv.y * mv.y; x[2] = inv.z * mv.z; x[3] = inv.w * mv.w;
    y[0] = sc[idx[i0 + 0]] * mv.x;
    y[1] = sc[idx[i0 + 1]] * mv.y;
    y[2] = sc[idx[i0 + 2]] * mv.z;
    y[3] = sc[idx[i0 + 3]] * mv.w;
    ushort4 xh, xl, yh, yl;
    #pragma unroll
    for (int j = 0; j < 4; ++j) {
        unsigned short h = f2bf(x[j]);
        float hf = __uint_as_float((unsigned int)h << 16);
        ((unsigned short*)&xh)[j] = h;
        ((unsigned short*)&xl)[j] = f2bf(x[j] - hf);
        unsigned short h2 = f2bf(y[j]);
        float hf2 = __uint_as_float((unsigned int)h2 << 16);
        ((unsigned short*)&yh)[j] = h2;
        ((unsigned short*)&yl)[j] = f2bf(y[j] - hf2);
    }
    *(ushort4*)&XmH[base] = xh;
    *(ushort4*)&XmL[base] = xl;
    *(ushort4*)&YmH[base] = yh;
    *(ushort4*)&YmL[base] = yl;
}

// ---------------- MFMA dual-gram diff: 64x64 tiles x 32 pos-slices ----------------
// R2-proven dbuf structure + counted-vmcnt discipline (same as egemm).
// Upper-triangle tiles only; compact coalesced output via LDS restage.
__global__ void __launch_bounds__(256)
gram_mfma(const unsigned short* __restrict__ XH, const unsigned short* __restrict__ XL,
          const unsigned short* __restrict__ YH, const unsigned short* __restrict__ YL,
          float* __restrict__ Dpart) {
    __shared__ short sm[32768];   // 2 buf x 8 arrays x [64][32] bf16 = 64 KB
    const int PI[10] = {0,0,0,0,1,1,1,2,2,3};
    const int PJ[10] = {0,1,2,3,1,2,3,2,3,3};
    int pr = blockIdx.x, sl = blockIdx.y;
    int ti = PI[pr], tj = PJ[pr];
    int c0 = ti * 64, d0 = tj * 64;
    int t = threadIdx.x, lane = t & 63, wv = t >> 6;
    int wr = wv >> 1, wc = wv & 1;
    int rowLoc = wv * 16 + (lane >> 2);                  // 0..63
    int kc2 = (((lane & 3) ^ ((lane >> 3) & 3))) << 3;
    int krd = (((lane >> 4) ^ ((lane >> 1) & 3))) << 3;
    int posBase = sl * 128 + kc2;

    const unsigned short* g0 = XH + (size_t)(c0 + rowLoc) * NPOS + posBase;
    const unsigned short* g1 = XL + (size_t)(c0 + rowLoc) * NPOS + posBase;
    const unsigned short* g2 = XH + (size_t)(d0 + rowLoc) * NPOS + posBase;
    const unsigned short* g3 = XL + (size_t)(d0 + rowLoc) * NPOS + posBase;
    const unsigned short* g4 = YH + (size_t)(c0 + rowLoc) * NPOS + posBase;
    const unsigned short* g5 = YL + (size_t)(c0 + rowLoc) * NPOS + posBase;
    const unsigned short* g6 = YH + (size_t)(d0 + rowLoc) * NPOS + posBase;
    const unsigned short* g7 = YL + (size_t)(d0 + rowLoc) * NPOS + posBase;
    int lb = wv * 512;

    auto STAGE = [&](short* base, int koff) {
        gload16(g0 + koff, base + lb);
        gload16(g1 + koff, base + 2048 + lb);
        gload16(g2 + koff, base + 4096 + lb);
        gload16(g3 + koff, base + 6144 + lb);
        gload16(g4 + koff, base + 8192 + lb);
        gload16(g5 + koff, base + 10240 + lb);
        gload16(g6 + koff, base + 12288 + lb);
        gload16(g7 + koff, base + 14336 + lb);
    };

    f32x4 aX[2][2], aY[2][2];
    #pragma unroll
    for (int mt = 0; mt < 2; ++mt)
        #pragma unroll
        for (int nt = 0; nt < 2; ++nt) {
            aX[mt][nt] = (f32x4){0.f, 0.f, 0.f, 0.f};
            aY[mt][nt] = (f32x4){0.f, 0.f, 0.f, 0.f};
        }

    STAGE(sm, 0);

    #pragma unroll
    for (int ks = 0; ks < 4; ++ks) {
        short* cb = sm + (ks & 1) * 16384;
        if (ks < 3) {
            STAGE(sm + ((ks + 1) & 1) * 16384, (ks + 1) * 32);
            asm volatile("s_waitcnt vmcnt(8)" ::: "memory");
        } else {
            asm volatile("s_waitcnt vmcnt(0)" ::: "memory");
        }
        __builtin_amdgcn_s_barrier();
        __builtin_amdgcn_sched_barrier(0);

        bf16x8 xcH[2], xcL[2], xdH[2], xdL[2], ycH[2], ycL[2], ydH[2], ydL[2];
        #pragma unroll
        for (int mt = 0; mt < 2; ++mt) {
            int off = (wr * 32 + mt * 16 + (lane & 15)) * 32 + krd;
            xcH[mt] = *(const bf16x8*)(cb + off);
            xcL[mt] = *(const bf16x8*)(cb + 2048 + off);
            ycH[mt] = *(const bf16x8*)(cb + 8192 + off);
            ycL[mt] = *(const bf16x8*)(cb + 10240 + off);
        }
        #pragma unroll
        for (int nt = 0; nt < 2; ++nt) {
            int off = (wc * 32 + nt * 16 + (lane & 15)) * 32 + krd;
            xdH[nt] = *(const bf16x8*)(cb + 4096 + off);
            xdL[nt] = *(const bf16x8*)(cb + 6144 + off);
            ydH[nt] = *(const bf16x8*)(cb + 12288 + off);
            ydL[nt] = *(const bf16x8*)(cb + 14336 + off);
        }
        __builtin_amdgcn_s_setprio(1);
        #pragma unroll
        for (int mt = 0; mt < 2; ++mt)
            #pragma unroll
            for (int nt = 0; nt < 2; ++nt) {
                f32x4 cx = aX[mt][nt];
                cx = __builtin_amdgcn_mfma_f32_16x16x32_bf16(xcH[mt], xdH[nt], cx, 0, 0, 0);
                cx = __builtin_amdgcn_mfma_f32_16x16x32_bf16(xcH[mt], xdL[nt], cx, 0, 0, 0);
                cx = __builtin_amdgcn_mfma_f32_16x16x32_bf16(xcL[mt], xdH[nt], cx, 0, 0, 0);
                aX[mt][nt] = cx;
                f32x4 cy = aY[mt][nt];
                cy = __builtin_amdgcn_mfma_f32_16x16x32_bf16(ycH[mt], ydH[nt], cy, 0, 0, 0);
                cy = __builtin_amdgcn_mfma_f32_16x16x32_bf16(ycH[mt], ydL[nt], cy, 0, 0, 0);
                cy = __builtin_amdgcn_mfma_f32_16x16x32_bf16(ycL[mt], ydH[nt], cy, 0, 0, 0);
                aY[mt][nt] = cy;
            }
        __builtin_amdgcn_s_setprio(0);

        asm volatile("s_waitcnt lgkmcnt(0)" ::: "memory");
        __builtin_amdgcn_s_barrier();
        __builtin_amdgcn_sched_barrier(0);
    }

    // ---- coalesced epilogue: 64x64 diff tile via LDS (stride 68), float4 out ----
    float* fs = (float*)sm;                      // 64*68*4 = 17.4KB < 64KB
    #pragma unroll
    for (int mt = 0; mt < 2; ++mt) {
        int rl = wr * 32 + mt * 16 + ((lane >> 4) << 2);
        #pragma unroll
        for (int nt = 0; nt < 2; ++nt) {
            int cl = wc * 32 + nt * 16 + (lane & 15);
            #pragma unroll
            for (int r2 = 0; r2 < 4; ++r2)
                fs[(rl + r2) * 68 + cl] = aX[mt][nt][r2] - aY[mt][nt][r2];
        }
    }
    __syncthreads();
    float* Db = Dpart + ((size_t)sl * 10 + pr) * 4096;
    int rr0 = t >> 4;              // 0..15
    int cc0 = (t & 15) << 2;       // 0..60
    #pragma unroll
    for (int i = 0; i < 4; ++i) {
        int rr = rr0 + (i << 4);
        *(float4*)&Db[rr * 64 + cc0] = *(const float4*)&fs[rr * 68 + cc0];
    }
}

// ---------------- final loss (mask-sum fused; upper-tile iteration, off-diag x2) ----------------
__global__ void __launch_bounds__(256)
loss_kernel(const float* __restrict__ Dpart, const float* __restrict__ mask,
            float* __restrict__ out) {
    const int PI[10] = {0,0,0,0,1,1,1,2,2,3};
    const int PJ[10] = {0,1,2,3,1,2,3,2,3,3};
    __shared__ float red[4];
    int tid = threadIdx.x;

    // redundant per-block mask sum (16KB read; replaces separate msum kernel)
    float ms = 0.f;
    for (int i = tid; i < NPOS; i += 256) ms += mask[i];
    #pragma unroll
    for (int o = 32; o >= 1; o >>= 1) ms += __shfl_down(ms, o, 64);
    if ((tid & 63) == 0) red[tid >> 6] = ms;
    __syncthreads();
    float msum = 256.0f * (red[0] + red[1] + red[2] + red[3]);
    __syncthreads();                    // red[] reused below

    int e2 = blockIdx.x * 256 + tid;    // grid 160: 10 tiles x 4096
    int tt = e2 >> 12;                  // uniform within block
    int ei = e2 & 4095;
    float d = 0.f;
    #pragma unroll
    for (int s = 0; s < GSLICE; ++s)
        d += Dpart[(size_t)(s * 10 + tt) * 4096 + ei];
    float inv = 1.0f / msum;
    float v = d * inv;
    float w = (PI[tt] != PJ[tt]) ? 2.0f : 1.0f;
    float ls = w * v * v;
    #pragma unroll
    for (int o = 32; o >= 1; o >>= 1) ls += __shfl_down(ls, o, 64);
    if ((tid & 63) == 0) red[tid >> 6] = ls;
    __syncthreads();
    if (tid == 0)
        atomicAdd(out, (red[0] + red[1] + red[2] + red[3]) * (100.0f / 65536.0f));
}

extern "C" void kernel_launch(void* const* d_in, const int* in_sizes, int n_in,
                              void* d_out, int out_size, void* d_ws, size_t ws_size,
                              hipStream_t stream) {
    (void)in_sizes; (void)n_in; (void)out_size;
    const float* content = (const float*)d_in[0];
    const float* style   = (const float*)d_in[1];
    const float* input   = (const float*)d_in[2];
    const float* mask    = (const float*)d_in[3];
    float* out = (float*)d_out;

    auto alignup = [](size_t b) { return (b + 255) & ~size_t(255); };

    size_t szT   = alignup((size_t)PAD_HW * C_CH * 2);
    size_t szSS  = alignup((size_t)8 * NPOS * 4);
    size_t szRS  = alignup((size_t)NPOS * 4);
    size_t szPV  = alignup((size_t)256 * NPOS * 4);
    size_t szIdx = alignup((size_t)NPOS * 4);
    size_t szXYb = alignup((size_t)C_CH * NPOS * 2);    // bf16 H/L arrays
    size_t szDp  = alignup((size_t)GSLICE * 10 * 4096 * 4);
    size_t fixed = 4 * szT + szSS + szRS + 2 * szPV + szIdx + 4 * szXYb + szDp;

    // E row stride padded to a multiple of 16 floats (64B) -> full-line stores
    auto padcols = [](int c) { return (c + 15) & ~15; };

    auto needE = [&](int NG) {
        size_t Nc = (size_t)padcols((64 / NG + 2) * PAD_W);
        return fixed + alignup((size_t)PAD_HW * Nc * 4) + 4096;
    };
    // R6 lesson: NG=2 regressed (launch serialization + tails). NG=1 is best.
    int NG = 8;
    if      (ws_size >= needE(1)) NG = 1;
    else if (ws_size >= needE(2)) NG = 2;
    else if (ws_size >= needE(4)) NG = 4;
    int R = 64 / NG;
    int colLim = (R + 2) * PAD_W;          // real columns
    int Ncols = padcols(colLim);           // padded row stride

    char* ws = (char*)d_ws;
    size_t off = 0;
    auto alloc = [&](size_t bytes) { void* p = ws + off; off += alignup(bytes); return p; };

    unsigned short* cTH = (unsigned short*)alloc((size_t)PAD_HW * C_CH * 2);
    unsigned short* cTL = (unsigned short*)alloc((size_t)PAD_HW * C_CH * 2);
    unsigned short* sTH = (unsigned short*)alloc((size_t)PAD_HW * C_CH * 2);
    unsigned short* sTL = (unsigned short*)alloc((size_t)PAD_HW * C_CH * 2);
    float* SSp   = (float*)alloc((size_t)8 * NPOS * 4);
    float* rs    = (float*)alloc((size_t)NPOS * 4);
    float* pval  = (float*)alloc((size_t)256 * NPOS * 4);
    int*   pidx  = (int*)  alloc((size_t)256 * NPOS * 4);
    int*   idx   = (int*)  alloc((size_t)NPOS * 4);
    unsigned short* XmH = (unsigned short*)alloc((size_t)C_CH * NPOS * 2);
    unsigned short* XmL = (unsigned short*)alloc((size_t)C_CH * NPOS * 2);
    unsigned short* YmH = (unsigned short*)alloc((size_t)C_CH * NPOS * 2);
    unsigned short* YmL = (unsigned short*)alloc((size_t)C_CH * NPOS * 2);
    float* Dpart = (float*)alloc((size_t)GSLICE * 10 * 4096 * 4);
    float* E     = (float*)alloc((size_t)PAD_HW * Ncols * 4);

    hipMemsetAsync(d_out, 0, sizeof(float), stream);

    split_kernel<<<dim3(69, 4, 2), 256, 0, stream>>>(content, style, cTH, cTL, sTH, sTL);
    ssp_kernel<<<dim3(16, 8), 256, 0, stream>>>(style, SSp);
    rs_kernel<<<16, 256, 0, stream>>>(SSp, rs);

    int gx = (colLim + 127) / 128;
    int gy = (PAD_HW + 127) / 128;
    int nwg = gx * gy;
    for (int g = 0; g < NG; ++g) {
        int colBaseQ = g * R * PAD_W;
        egemm_mfma<<<nwg, 512, 0, stream>>>(cTH, cTL, sTH, sTL, E, colBaseQ, colLim, Ncols, gx, nwg);
        score_argmax<<<R * (64 / CHUNK), 256, 0, stream>>>(E, rs, pval, pidx, g, R, Ncols);
    }
    argmax_reduce_kernel<<<64, 256, 0, stream>>>(pval, pidx, idx);
    build_xy_kernel<<<1024, 256, 0, stream>>>(input, style, mask, idx, XmH, XmL, YmH, YmL);
    gram_mfma<<<dim3(10, GSLICE), 256, 0, stream>>>(XmH, XmL, YmH, YmL, Dpart);
    loss_kernel<<<160, 256, 0, stream>>>(Dpart, mask, out);
}

// Round 8
// 119.260 us; speedup vs baseline: 1.3309x; 1.1866x over previous
//
#include <hip/hip_runtime.h>
#include <math.h>

#define C_CH 256
#define NPOS 4096              // 64*64 spatial positions
#define PAD_W 66
#define PAD_HW (PAD_W*PAD_W)   // 4356
#define GSLICE 32              // gram position-axis slices (128 pos each)
#define CHUNK 8                // diagonal steps per score block

typedef __bf16 bf16x8 __attribute__((ext_vector_type(8)));
typedef float  f32x4  __attribute__((ext_vector_type(4)));

__device__ __forceinline__ int reflect_idx(int p) {
    int s = p - 1;
    if (s < 0) s = -s;
    if (s > 63) s = 126 - s;
    return s;
}

__device__ __forceinline__ unsigned short f2bf(float x) {
    unsigned int u = __float_as_uint(x);
    unsigned int r = u + 0x7fffu + ((u >> 16) & 1u);
    return (unsigned short)(r >> 16);
}

// monotone f32 -> u32 map: a < b  <=>  mono(a) < mono(b)
__device__ __forceinline__ unsigned int fmono(float f) {
    unsigned int b = __float_as_uint(f);
    return (b & 0x80000000u) ? ~b : (b | 0x80000000u);
}

// async global->LDS, 16B per lane; LDS dest = wave-uniform base + lane*16
__device__ __forceinline__ void gload16(const void* g, void* l) {
    __builtin_amdgcn_global_load_lds(
        (const __attribute__((address_space(1))) unsigned int*)g,
        (__attribute__((address_space(3))) unsigned int*)l, 16, 0, 0);
}

// ---------------- transpose + hi/lo bf16 split (z<2) + style sq-sums (z==2) ----------------
__global__ void __launch_bounds__(256)
split_kernel(const float* __restrict__ content, const float* __restrict__ style,
             unsigned short* __restrict__ cTH, unsigned short* __restrict__ cTL,
             unsigned short* __restrict__ sTH, unsigned short* __restrict__ sTL,
             float* __restrict__ SSp) {
    __shared__ float tile[64][65];
    int t = threadIdx.x;

    if (blockIdx.z == 2) {             // fused ssp: 128 logical blocks
        int bi = blockIdx.y * 69 + blockIdx.x;
        if (bi >= 128) return;
        int pos = ((bi & 15) << 8) + t;
        int cg = bi >> 4;              // 0..7
        float s = 0.f;
        for (int c = cg * 32; c < cg * 32 + 32; ++c) {
            float v = style[(size_t)c * NPOS + pos];
            s += v * v;
        }
        SSp[cg * NPOS + pos] = s;
        return;
    }

    const float* src = blockIdx.z ? style : content;
    unsigned short* oH = blockIdx.z ? sTH : cTH;
    unsigned short* oL = blockIdx.z ? sTL : cTL;
    int p0 = blockIdx.x * 64, c0 = blockIdx.y * 64;
    int posl = t & 63;
    int p = p0 + posl; int pc = p < PAD_HW ? p : PAD_HW - 1;
    int py = pc / PAD_W, px = pc - py * PAD_W;
    int rawIdx = reflect_idx(py) * 64 + reflect_idx(px);
    #pragma unroll
    for (int r = 0; r < 16; ++r) {
        int cl = (t >> 6) + r * 4;
        tile[posl][cl] = src[(size_t)(c0 + cl) * NPOS + rawIdx];
    }
    __syncthreads();
    int cl2 = t & 63;
    #pragma unroll
    for (int r = 0; r < 16; ++r) {
        int pl = (t >> 6) + r * 4;
        int pg = p0 + pl;
        if (pg < PAD_HW) {
            float x = tile[pl][cl2];
            unsigned short h = f2bf(x);
            float hf = __uint_as_float((unsigned int)h << 16);
            unsigned short l = f2bf(x - hf);
            oH[(size_t)pg * C_CH + c0 + cl2] = h;
            oL[(size_t)pg * C_CH + c0 + cl2] = l;
        }
    }
}

// ---------------- style patch inverse norms ----------------
__global__ void rs_kernel(const float* __restrict__ SSp, float* __restrict__ rs) {
    int j = blockIdx.x * blockDim.x + threadIdx.x;
    if (j >= NPOS) return;
    int yj = j >> 6, xj = j & 63;
    float s = 0.f;
    #pragma unroll
    for (int kh = 0; kh < 3; ++kh) {
        int ry = reflect_idx(yj + kh);
        #pragma unroll
        for (int kw = 0; kw < 3; ++kw) {
            int p = ry * 64 + reflect_idx(xj + kw);
            #pragma unroll
            for (int part = 0; part < 8; ++part)
                s += SSp[part * NPOS + p];
        }
    }
    rs[j] = 1.0f / sqrtf(s);
}

// ---------------- split-bf16 MFMA E-GEMM: 8-wave blocks (R7 structure) ----------------
__global__ void __launch_bounds__(512, 4)
egemm_mfma(const unsigned short* __restrict__ AH, const unsigned short* __restrict__ AL,
           const unsigned short* __restrict__ BH, const unsigned short* __restrict__ BL,
           float* __restrict__ E, int colBaseQ, int colLim, int Ncols, int gx, int nwg) {
    __shared__ short sm[32768];                 // 2 buffers x 4 arrays x [128][32] bf16 = 64KB

    int orig = blockIdx.x;
    int q = nwg >> 3, r = nwg & 7;
    int xcd = orig & 7, rank = orig >> 3;
    int L = (xcd < r ? xcd * (q + 1) : r * (q + 1) + (xcd - r) * q) + rank;
    int by = L / gx, bx = L - by * gx;

    int t = threadIdx.x;
    int lane = t & 63, wv = t >> 6;              // 8 waves
    int wr = wv >> 2, wc = wv & 3;               // wave tile: 64 rows x 32 cols
    int bm = by * 128, bn = bx * 128;
    int rowLoc = lane >> 2;                      // 0..15 within a 16-row block
    int kc2 = (((lane & 3) ^ ((lane >> 3) & 3))) << 3;   // swizzled src k-offset (elems)
    int krd = (((lane >> 4) ^ ((lane >> 1) & 3))) << 3;  // swizzled frag-read k-offset

    const unsigned short* mats[4] = {AH, AL, BH, BL};
    const unsigned short* M = mats[wv >> 1];
    int rbase = ((wv >> 1) >= 2 ? colBaseQ + bn : bm) + (wv & 1) * 64;
    const unsigned short* gp[4];
    #pragma unroll
    for (int i = 0; i < 4; ++i) {
        int rr = rbase + i * 16 + rowLoc;
        if (rr > PAD_HW - 1) rr = PAD_HW - 1;
        gp[i] = M + (size_t)rr * C_CH + kc2;
    }
    int ldst = wv * 2048;                        // shorts: wave's half-array base

    auto STAGE = [&](short* base, int koff) {
        #pragma unroll
        for (int i = 0; i < 4; ++i)
            gload16(gp[i] + koff, base + ldst + i * 512);
    };

    f32x4 acc[4][2];
    #pragma unroll
    for (int mt = 0; mt < 4; ++mt)
        #pragma unroll
        for (int nt = 0; nt < 2; ++nt)
            acc[mt][nt] = (f32x4){0.f, 0.f, 0.f, 0.f};

    STAGE(sm, 0);                                // tile 0: 4 loads in flight/wave

    #pragma unroll
    for (int ks = 0; ks < 8; ++ks) {
        short* cb = sm + (ks & 1) * 16384;
        if (ks < 7) {
            STAGE(sm + ((ks + 1) & 1) * 16384, (ks + 1) * 32);   // +4 in flight
            asm volatile("s_waitcnt vmcnt(4)" ::: "memory");     // tile ks landed
        } else {
            asm volatile("s_waitcnt vmcnt(0)" ::: "memory");
        }
        __builtin_amdgcn_s_barrier();
        __builtin_amdgcn_sched_barrier(0);

        short* sAH = cb;
        short* sAL = cb + 4096;
        short* sBH = cb + 8192;
        short* sBL = cb + 12288;
        bf16x8 aH[4], aL[4], bH[2], bL[2];
        #pragma unroll
        for (int mt = 0; mt < 4; ++mt) {
            int off = (wr * 64 + mt * 16 + (lane & 15)) * 32 + krd;
            aH[mt] = *(const bf16x8*)(sAH + off);
            aL[mt] = *(const bf16x8*)(sAL + off);
        }
        #pragma unroll
        for (int nt = 0; nt < 2; ++nt) {
            int off = (wc * 32 + nt * 16 + (lane & 15)) * 32 + krd;
            bH[nt] = *(const bf16x8*)(sBH + off);
            bL[nt] = *(const bf16x8*)(sBL + off);
        }
        __builtin_amdgcn_s_setprio(1);
        #pragma unroll
        for (int mt = 0; mt < 4; ++mt)
            #pragma unroll
            for (int nt = 0; nt < 2; ++nt) {
                f32x4 c = acc[mt][nt];
                c = __builtin_amdgcn_mfma_f32_16x16x32_bf16(aH[mt], bH[nt], c, 0, 0, 0);
                c = __builtin_amdgcn_mfma_f32_16x16x32_bf16(aH[mt], bL[nt], c, 0, 0, 0);
                c = __builtin_amdgcn_mfma_f32_16x16x32_bf16(aL[mt], bH[nt], c, 0, 0, 0);
                acc[mt][nt] = c;
            }
        __builtin_amdgcn_s_setprio(0);

        asm volatile("s_waitcnt lgkmcnt(0)" ::: "memory");
        __builtin_amdgcn_s_barrier();
        __builtin_amdgcn_sched_barrier(0);
    }

    // ---- direct store: padded Ncols makes each 16-lane run a full 64B line ----
    #pragma unroll
    for (int mt = 0; mt < 4; ++mt) {
        int row0 = bm + wr * 64 + mt * 16 + (lane >> 4) * 4;
        #pragma unroll
        for (int nt = 0; nt < 2; ++nt) {
            int col = bn + wc * 32 + nt * 16 + (lane & 15);
            if (col < colLim) {
                #pragma unroll
                for (int r2 = 0; r2 < 4; ++r2) {
                    int row = row0 + r2;
                    if (row < PAD_HW)
                        E[(size_t)row * Ncols + col] = acc[mt][nt][r2];
                }
            }
        }
    }
}

// ---------------- fused 9-tap score + normalize + packed-atomic argmax ----------------
// pval/pidx partial arrays replaced by one u64 per position: (mono(score)<<32)|~j.
// atomicMax gives max-score with lowest-j tie-break == jnp.argmax semantics.
__global__ void __launch_bounds__(256)
score_argmax(const float* __restrict__ E, const float* __restrict__ rs,
             unsigned long long* __restrict__ PK,
             int g, int R, int Ncols) {
    __shared__ float T[3 * 66 * 68];   // 3 strip buffers, stride 68
    __shared__ float sv[4][64];
    __shared__ int   sj[4][64];

    int bid = blockIdx.x;
    int d = bid % R;                   // diagonal
    int c = bid / R;                   // chunk
    int s0 = c * CHUNK;
    int t = threadIdx.x;
    int xi = t & 63, s2 = t >> 6, xj0 = s2 * 16;

    int u0 = t / 66, v0 = t - u0 * 66; // walk base for e = t + 256*i

    bool valid = false;
    float r[18];

    for (int s = s0; s < s0 + CHUNK; ++s) {
        int yjl = (s + d) & (R - 1);

        if (!valid) {                  // warmup / post-wrap: load 3 strips
            __syncthreads();
            for (int kh = 0; kh < 3; ++kh) {
                float* Tb = T + ((s + kh) % 3) * 4488;
                const float* Eb = E + (size_t)((s + kh) * 66) * Ncols + (yjl + kh) * 66;
                int u = u0, v = v0;
                #pragma unroll
                for (int i = 0; i < 17; ++i) {
                    Tb[u * 68 + v] = Eb[(size_t)u * Ncols + v];
                    v += 58; u += 3; if (v >= 66) { v -= 66; ++u; }
                }
                if (t < 4) Tb[65 * 68 + 62 + t] = Eb[(size_t)65 * Ncols + 62 + t];
            }
            __syncthreads();
            valid = true;
        }

        // prefetch next step's new strip into regs (issue before compute)
        int yjl_next = (s + 1 + d) & (R - 1);
        bool pf = (s + 1 < s0 + CHUNK) && (yjl_next == yjl + 1);
        if (pf) {
            const float* Eb = E + (size_t)((s + 3) * 66) * Ncols + (yjl + 3) * 66;
            int u = u0, v = v0;
            #pragma unroll
            for (int i = 0; i < 17; ++i) {
                r[i] = Eb[(size_t)u * Ncols + v];
                v += 58; u += 3; if (v >= 66) { v -= 66; ++u; }
            }
            if (t < 4) r[17] = Eb[(size_t)65 * Ncols + 62 + t];
        }

        // compute 9-tap scores for this (yi=s, yjl): register row-windows
        float sc[16];
        #pragma unroll
        for (int q2 = 0; q2 < 16; ++q2) sc[q2] = 0.f;
        #pragma unroll
        for (int kh = 0; kh < 3; ++kh) {
            const float* Tk = T + ((s + kh) % 3) * 4488;
            #pragma unroll
            for (int kw = 0; kw < 3; ++kw) {
                const float* rp = Tk + (xi + kw) * 68 + xj0;
                float rr[18];
                *(float4*)&rr[0]  = *(const float4*)&rp[0];
                *(float4*)&rr[4]  = *(const float4*)&rp[4];
                *(float4*)&rr[8]  = *(const float4*)&rp[8];
                *(float4*)&rr[12] = *(const float4*)&rp[12];
                if (kw > 0) *(float2*)&rr[16] = *(const float2*)&rp[16];
                #pragma unroll
                for (int q2 = 0; q2 < 16; ++q2) sc[q2] += rr[kw + q2];
            }
        }

        // normalize + local argmax over this thread's 16 xj
        int jbase = ((g * R + yjl) << 6) + xj0;
        float bv = -INFINITY; int bj = 0;
        #pragma unroll
        for (int q2 = 0; q2 < 16; ++q2) {
            float v = sc[q2] * rs[jbase + q2];
            if (v > bv) { bv = v; bj = jbase + q2; }
        }
        // s2-reduction in LDS, then ONE packed atomicMax per position
        sv[s2][xi] = bv; sj[s2][xi] = bj;
        __syncthreads();
        if (s2 == 0) {
            #pragma unroll
            for (int u = 1; u < 4; ++u) {
                float ov = sv[u][xi]; int oj = sj[u][xi];
                if (ov > bv || (ov == bv && oj < bj)) { bv = ov; bj = oj; }
            }
            unsigned long long pk =
                ((unsigned long long)fmono(bv) << 32) | (unsigned int)(~bj);
            atomicMax(PK + (s << 6) + xi, pk);
        }

        if (pf) {                      // drain prefetch into freed buffer
            __syncthreads();
            float* Tb = T + ((s + 3) % 3) * 4488;
            int u = u0, v = v0;
            #pragma unroll
            for (int i = 0; i < 17; ++i) {
                Tb[u * 68 + v] = r[i];
                v += 58; u += 3; if (v >= 66) { v -= 66; ++u; }
            }
            if (t < 4) Tb[65 * 68 + 62 + t] = r[17];
            __syncthreads();
        } else {
            valid = false;
        }
    }
}

// ---------------- build masked matrices as split-bf16 H/L [c][4096] ----------------
__global__ void __launch_bounds__(256)
build_xy_kernel(const float* __restrict__ input_fm,
                const float* __restrict__ style,
                const float* __restrict__ mask,
                const unsigned long long* __restrict__ PK,
                unsigned short* __restrict__ XmH, unsigned short* __restrict__ XmL,
                unsigned short* __restrict__ YmH, unsigned short* __restrict__ YmL) {
    int e4 = blockIdx.x * 256 + threadIdx.x;    // grid 1024: C_CH*NPOS/4
    int c = e4 >> 10;
    int i0 = (e4 & 1023) << 2;
    int base = (c << 12) + i0;
    float4 inv = *(const float4*)&input_fm[base];
    float4 mv  = *(const float4*)&mask[i0];
    const float* sc = style + ((size_t)c << 12);
    float x[4], y[4];
    x[0] = inv.x * mv.x; x[1] = inv.y * mv.y; x[2] = inv.z * mv.z; x[3] = inv.w * mv.w;
    float mvv[4] = {mv.x, mv.y, mv.z, mv.w};
    #pragma unroll
    for (int k = 0; k < 4; ++k) {
        unsigned long long pk = PK[i0 + k];
        int j = (int)(~(unsigned int)(pk & 0xffffffffu));
        y[k] = sc[j] * mvv[k];
    }
    ushort4 xh, xl, yh, yl;
    #pragma unroll
    for (int j = 0; j < 4; ++j) {
        unsigned short h = f2bf(x[j]);
        float hf = __uint_as_float((unsigned int)h << 16);
        ((unsigned short*)&xh)[j] = h;
        ((unsigned short*)&xl)[j] = f2bf(x[j] - hf);
        unsigned short h2 = f2bf(y[j]);
        float hf2 = __uint_as_float((unsigned int)h2 << 16);
        ((unsigned short*)&yh)[j] = h2;
        ((unsigned short*)&yl)[j] = f2bf(y[j] - hf2);
    }
    *(ushort4*)&XmH[base] = xh;
    *(ushort4*)&XmL[base] = xl;
    *(ushort4*)&YmH[base] = yh;
    *(ushort4*)&YmL[base] = yl;
}

// ---------------- MFMA dual-gram diff: 64x64 tiles x 32 pos-slices ----------------
__global__ void __launch_bounds__(256)
gram_mfma(const unsigned short* __restrict__ XH, const unsigned short* __restrict__ XL,
          const unsigned short* __restrict__ YH, const unsigned short* __restrict__ YL,
          float* __restrict__ Dpart) {
    __shared__ short sm[32768];   // 2 buf x 8 arrays x [64][32] bf16 = 64 KB
    const int PI[10] = {0,0,0,0,1,1,1,2,2,3};
    const int PJ[10] = {0,1,2,3,1,2,3,2,3,3};
    int pr = blockIdx.x, sl = blockIdx.y;
    int ti = PI[pr], tj = PJ[pr];
    int c0 = ti * 64, d0 = tj * 64;
    int t = threadIdx.x, lane = t & 63, wv = t >> 6;
    int wr = wv >> 1, wc = wv & 1;
    int rowLoc = wv * 16 + (lane >> 2);                  // 0..63
    int kc2 = (((lane & 3) ^ ((lane >> 3) & 3))) << 3;
    int krd = (((lane >> 4) ^ ((lane >> 1) & 3))) << 3;
    int posBase = sl * 128 + kc2;

    const unsigned short* g0 = XH + (size_t)(c0 + rowLoc) * NPOS + posBase;
    const unsigned short* g1 = XL + (size_t)(c0 + rowLoc) * NPOS + posBase;
    const unsigned short* g2 = XH + (size_t)(d0 + rowLoc) * NPOS + posBase;
    const unsigned short* g3 = XL + (size_t)(d0 + rowLoc) * NPOS + posBase;
    const unsigned short* g4 = YH + (size_t)(c0 + rowLoc) * NPOS + posBase;
    const unsigned short* g5 = YL + (size_t)(c0 + rowLoc) * NPOS + posBase;
    const unsigned short* g6 = YH + (size_t)(d0 + rowLoc) * NPOS + posBase;
    const unsigned short* g7 = YL + (size_t)(d0 + rowLoc) * NPOS + posBase;
    int lb = wv * 512;

    auto STAGE = [&](short* base, int koff) {
        gload16(g0 + koff, base + lb);
        gload16(g1 + koff, base + 2048 + lb);
        gload16(g2 + koff, base + 4096 + lb);
        gload16(g3 + koff, base + 6144 + lb);
        gload16(g4 + koff, base + 8192 + lb);
        gload16(g5 + koff, base + 10240 + lb);
        gload16(g6 + koff, base + 12288 + lb);
        gload16(g7 + koff, base + 14336 + lb);
    };

    f32x4 aX[2][2], aY[2][2];
    #pragma unroll
    for (int mt = 0; mt < 2; ++mt)
        #pragma unroll
        for (int nt = 0; nt < 2; ++nt) {
            aX[mt][nt] = (f32x4){0.f, 0.f, 0.f, 0.f};
            aY[mt][nt] = (f32x4){0.f, 0.f, 0.f, 0.f};
        }

    STAGE(sm, 0);

    #pragma unroll
    for (int ks = 0; ks < 4; ++ks) {
        short* cb = sm + (ks & 1) * 16384;
        if (ks < 3) {
            STAGE(sm + ((ks + 1) & 1) * 16384, (ks + 1) * 32);
            asm volatile("s_waitcnt vmcnt(8)" ::: "memory");
        } else {
            asm volatile("s_waitcnt vmcnt(0)" ::: "memory");
        }
        __builtin_amdgcn_s_barrier();
        __builtin_amdgcn_sched_barrier(0);

        bf16x8 xcH[2], xcL[2], xdH[2], xdL[2], ycH[2], ycL[2], ydH[2], ydL[2];
        #pragma unroll
        for (int mt = 0; mt < 2; ++mt) {
            int off = (wr * 32 + mt * 16 + (lane & 15)) * 32 + krd;
            xcH[mt] = *(const bf16x8*)(cb + off);
            xcL[mt] = *(const bf16x8*)(cb + 2048 + off);
            ycH[mt] = *(const bf16x8*)(cb + 8192 + off);
            ycL[mt] = *(const bf16x8*)(cb + 10240 + off);
        }
        #pragma unroll
        for (int nt = 0; nt < 2; ++nt) {
            int off = (wc * 32 + nt * 16 + (lane & 15)) * 32 + krd;
            xdH[nt] = *(const bf16x8*)(cb + 4096 + off);
            xdL[nt] = *(const bf16x8*)(cb + 6144 + off);
            ydH[nt] = *(const bf16x8*)(cb + 12288 + off);
            ydL[nt] = *(const bf16x8*)(cb + 14336 + off);
        }
        __builtin_amdgcn_s_setprio(1);
        #pragma unroll
        for (int mt = 0; mt < 2; ++mt)
            #pragma unroll
            for (int nt = 0; nt < 2; ++nt) {
                f32x4 cx = aX[mt][nt];
                cx = __builtin_amdgcn_mfma_f32_16x16x32_bf16(xcH[mt], xdH[nt], cx, 0, 0, 0);
                cx = __builtin_amdgcn_mfma_f32_16x16x32_bf16(xcH[mt], xdL[nt], cx, 0, 0, 0);
                cx = __builtin_amdgcn_mfma_f32_16x16x32_bf16(xcL[mt], xdH[nt], cx, 0, 0, 0);
                aX[mt][nt] = cx;
                f32x4 cy = aY[mt][nt];
                cy = __builtin_amdgcn_mfma_f32_16x16x32_bf16(ycH[mt], ydH[nt], cy, 0, 0, 0);
                cy = __builtin_amdgcn_mfma_f32_16x16x32_bf16(ycH[mt], ydL[nt], cy, 0, 0, 0);
                cy = __builtin_amdgcn_mfma_f32_16x16x32_bf16(ycL[mt], ydH[nt], cy, 0, 0, 0);
                aY[mt][nt] = cy;
            }
        __builtin_amdgcn_s_setprio(0);

        asm volatile("s_waitcnt lgkmcnt(0)" ::: "memory");
        __builtin_amdgcn_s_barrier();
        __builtin_amdgcn_sched_barrier(0);
    }

    // ---- coalesced epilogue: 64x64 diff tile via LDS (stride 68), float4 out ----
    float* fs = (float*)sm;                      // 64*68*4 = 17.4KB < 64KB
    #pragma unroll
    for (int mt = 0; mt < 2; ++mt) {
        int rl = wr * 32 + mt * 16 + ((lane >> 4) << 2);
        #pragma unroll
        for (int nt = 0; nt < 2; ++nt) {
            int cl = wc * 32 + nt * 16 + (lane & 15);
            #pragma unroll
            for (int r2 = 0; r2 < 4; ++r2)
                fs[(rl + r2) * 68 + cl] = aX[mt][nt][r2] - aY[mt][nt][r2];
        }
    }
    __syncthreads();
    float* Db = Dpart + ((size_t)sl * 10 + pr) * 4096;
    int rr0 = t >> 4;              // 0..15
    int cc0 = (t & 15) << 2;       // 0..60
    #pragma unroll
    for (int i = 0; i < 4; ++i) {
        int rr = rr0 + (i << 4);
        *(float4*)&Db[rr * 64 + cc0] = *(const float4*)&fs[rr * 68 + cc0];
    }
}

// ---------------- final loss (mask-sum fused; upper-tile iteration, off-diag x2) ----------------
__global__ void __launch_bounds__(256)
loss_kernel(const float* __restrict__ Dpart, const float* __restrict__ mask,
            float* __restrict__ out) {
    const int PI[10] = {0,0,0,0,1,1,1,2,2,3};
    const int PJ[10] = {0,1,2,3,1,2,3,2,3,3};
    __shared__ float red[4];
    int tid = threadIdx.x;

    float ms = 0.f;
    for (int i = tid; i < NPOS; i += 256) ms += mask[i];
    #pragma unroll
    for (int o = 32; o >= 1; o >>= 1) ms += __shfl_down(ms, o, 64);
    if ((tid & 63) == 0) red[tid >> 6] = ms;
    __syncthreads();
    float msum = 256.0f * (red[0] + red[1] + red[2] + red[3]);
    __syncthreads();                    // red[] reused below

    int e2 = blockIdx.x * 256 + tid;    // grid 160: 10 tiles x 4096
    int tt = e2 >> 12;                  // uniform within block
    int ei = e2 & 4095;
    float d = 0.f;
    #pragma unroll
    for (int s = 0; s < GSLICE; ++s)
        d += Dpart[(size_t)(s * 10 + tt) * 4096 + ei];
    float inv = 1.0f / msum;
    float v = d * inv;
    float w = (PI[tt] != PJ[tt]) ? 2.0f : 1.0f;
    float ls = w * v * v;
    #pragma unroll
    for (int o = 32; o >= 1; o >>= 1) ls += __shfl_down(ls, o, 64);
    if ((tid & 63) == 0) red[tid >> 6] = ls;
    __syncthreads();
    if (tid == 0)
        atomicAdd(out, (red[0] + red[1] + red[2] + red[3]) * (100.0f / 65536.0f));
}

extern "C" void kernel_launch(void* const* d_in, const int* in_sizes, int n_in,
                              void* d_out, int out_size, void* d_ws, size_t ws_size,
                              hipStream_t stream) {
    (void)in_sizes; (void)n_in; (void)out_size;
    const float* content = (const float*)d_in[0];
    const float* style   = (const float*)d_in[1];
    const float* input   = (const float*)d_in[2];
    const float* mask    = (const float*)d_in[3];
    float* out = (float*)d_out;

    auto alignup = [](size_t b) { return (b + 255) & ~size_t(255); };

    size_t szT   = alignup((size_t)PAD_HW * C_CH * 2);
    size_t szSS  = alignup((size_t)8 * NPOS * 4);
    size_t szRS  = alignup((size_t)NPOS * 4);
    size_t szPK  = alignup((size_t)NPOS * 8);
    size_t szXYb = alignup((size_t)C_CH * NPOS * 2);    // bf16 H/L arrays
    size_t szDp  = alignup((size_t)GSLICE * 10 * 4096 * 4);
    size_t fixed = 4 * szT + szSS + szRS + szPK + 4 * szXYb + szDp;

    // E row stride padded to a multiple of 16 floats (64B) -> full-line stores
    auto padcols = [](int c) { return (c + 15) & ~15; };

    auto needE = [&](int NG) {
        size_t Nc = (size_t)padcols((64 / NG + 2) * PAD_W);
        return fixed + alignup((size_t)PAD_HW * Nc * 4) + 4096;
    };
    // R6 lesson: NG=2 regressed (launch serialization + tails). NG=1 is best.
    int NG = 8;
    if      (ws_size >= needE(1)) NG = 1;
    else if (ws_size >= needE(2)) NG = 2;
    else if (ws_size >= needE(4)) NG = 4;
    int R = 64 / NG;
    int colLim = (R + 2) * PAD_W;          // real columns
    int Ncols = padcols(colLim);           // padded row stride

    char* ws = (char*)d_ws;
    size_t off = 0;
    auto alloc = [&](size_t bytes) { void* p = ws + off; off += alignup(bytes); return p; };

    unsigned short* cTH = (unsigned short*)alloc((size_t)PAD_HW * C_CH * 2);
    unsigned short* cTL = (unsigned short*)alloc((size_t)PAD_HW * C_CH * 2);
    unsigned short* sTH = (unsigned short*)alloc((size_t)PAD_HW * C_CH * 2);
    unsigned short* sTL = (unsigned short*)alloc((size_t)PAD_HW * C_CH * 2);
    float* SSp   = (float*)alloc((size_t)8 * NPOS * 4);
    float* rs    = (float*)alloc((size_t)NPOS * 4);
    unsigned long long* PK = (unsigned long long*)alloc((size_t)NPOS * 8);
    unsigned short* XmH = (unsigned short*)alloc((size_t)C_CH * NPOS * 2);
    unsigned short* XmL = (unsigned short*)alloc((size_t)C_CH * NPOS * 2);
    unsigned short* YmH = (unsigned short*)alloc((size_t)C_CH * NPOS * 2);
    unsigned short* YmL = (unsigned short*)alloc((size_t)C_CH * NPOS * 2);
    float* Dpart = (float*)alloc((size_t)GSLICE * 10 * 4096 * 4);
    float* E     = (float*)alloc((size_t)PAD_HW * Ncols * 4);

    hipMemsetAsync(d_out, 0, sizeof(float), stream);
    hipMemsetAsync(PK, 0, (size_t)NPOS * 8, stream);

    split_kernel<<<dim3(69, 4, 3), 256, 0, stream>>>(content, style, cTH, cTL, sTH, sTL, SSp);
    rs_kernel<<<16, 256, 0, stream>>>(SSp, rs);

    int gx = (colLim + 127) / 128;
    int gy = (PAD_HW + 127) / 128;
    int nwg = gx * gy;
    for (int g = 0; g < NG; ++g) {
        int colBaseQ = g * R * PAD_W;
        egemm_mfma<<<nwg, 512, 0, stream>>>(cTH, cTL, sTH, sTL, E, colBaseQ, colLim, Ncols, gx, nwg);
        score_argmax<<<R * (64 / CHUNK), 256, 0, stream>>>(E, rs, PK, g, R, Ncols);
    }
    build_xy_kernel<<<1024, 256, 0, stream>>>(input, style, mask, PK, XmH, XmL, YmH, YmL);
    gram_mfma<<<dim3(10, GSLICE), 256, 0, stream>>>(XmH, XmL, YmH, YmL, Dpart);
    loss_kernel<<<160, 256, 0, stream>>>(Dpart, mask, out);
}

// Round 9
// 109.240 us; speedup vs baseline: 1.4530x; 1.0917x over previous
//
#include <hip/hip_runtime.h>
#include <math.h>

#define C_CH 256
#define NPOS 4096              // 64*64 spatial positions
#define PAD_W 66
#define PAD_HW (PAD_W*PAD_W)   // 4356
#define GSLICE 32              // gram position-axis slices (128 pos each)
#define CHUNK 8                // diagonal steps per score block

typedef __bf16 bf16x8 __attribute__((ext_vector_type(8)));
typedef float  f32x4  __attribute__((ext_vector_type(4)));

__device__ __forceinline__ int reflect_idx(int p) {
    int s = p - 1;
    if (s < 0) s = -s;
    if (s > 63) s = 126 - s;
    return s;
}

__device__ __forceinline__ unsigned short f2bf(float x) {
    unsigned int u = __float_as_uint(x);
    unsigned int r = u + 0x7fffu + ((u >> 16) & 1u);
    return (unsigned short)(r >> 16);
}

// monotone f32 -> u32 map: a < b  <=>  mono(a) < mono(b)
__device__ __forceinline__ unsigned int fmono(float f) {
    unsigned int b = __float_as_uint(f);
    return (b & 0x80000000u) ? ~b : (b | 0x80000000u);
}

// async global->LDS, 16B per lane; LDS dest = wave-uniform base + lane*16
__device__ __forceinline__ void gload16(const void* g, void* l) {
    __builtin_amdgcn_global_load_lds(
        (const __attribute__((address_space(1))) unsigned int*)g,
        (__attribute__((address_space(3))) unsigned int*)l, 16, 0, 0);
}

// ---------------- transpose + hi/lo bf16 split (z<2) + style sq-sums (z==2) ----------------
__global__ void __launch_bounds__(256)
split_kernel(const float* __restrict__ content, const float* __restrict__ style,
             unsigned short* __restrict__ cTH, unsigned short* __restrict__ cTL,
             unsigned short* __restrict__ sTH, unsigned short* __restrict__ sTL,
             float* __restrict__ SSp) {
    __shared__ float tile[64][65];
    int t = threadIdx.x;

    if (blockIdx.z == 2) {             // fused ssp: 128 logical blocks
        int bi = blockIdx.y * 69 + blockIdx.x;
        if (bi >= 128) return;
        int pos = ((bi & 15) << 8) + t;
        int cg = bi >> 4;              // 0..7
        float s = 0.f;
        for (int c = cg * 32; c < cg * 32 + 32; ++c) {
            float v = style[(size_t)c * NPOS + pos];
            s += v * v;
        }
        SSp[cg * NPOS + pos] = s;
        return;
    }

    const float* src = blockIdx.z ? style : content;
    unsigned short* oH = blockIdx.z ? sTH : cTH;
    unsigned short* oL = blockIdx.z ? sTL : cTL;
    int p0 = blockIdx.x * 64, c0 = blockIdx.y * 64;
    int posl = t & 63;
    int p = p0 + posl; int pc = p < PAD_HW ? p : PAD_HW - 1;
    int py = pc / PAD_W, px = pc - py * PAD_W;
    int rawIdx = reflect_idx(py) * 64 + reflect_idx(px);
    #pragma unroll
    for (int r = 0; r < 16; ++r) {
        int cl = (t >> 6) + r * 4;
        tile[posl][cl] = src[(size_t)(c0 + cl) * NPOS + rawIdx];
    }
    __syncthreads();
    int cl2 = t & 63;
    #pragma unroll
    for (int r = 0; r < 16; ++r) {
        int pl = (t >> 6) + r * 4;
        int pg = p0 + pl;
        if (pg < PAD_HW) {
            float x = tile[pl][cl2];
            unsigned short h = f2bf(x);
            float hf = __uint_as_float((unsigned int)h << 16);
            unsigned short l = f2bf(x - hf);
            oH[(size_t)pg * C_CH + c0 + cl2] = h;
            oL[(size_t)pg * C_CH + c0 + cl2] = l;
        }
    }
}

// ---------------- split-bf16 MFMA E-GEMM: 8-wave blocks (R7 structure) ----------------
// R8 lesson: node elimination pays ~4-5us/node. Blocks orig<8 additionally
// compute rs[] (style patch inverse norms) and zero PK[] in a prologue --
// this deletes the rs_kernel node and the PK memset node. vmcnt(0) after the
// prologue restores the counted-vmcnt staging discipline.
__global__ void __launch_bounds__(512, 4)
egemm_mfma(const unsigned short* __restrict__ AH, const unsigned short* __restrict__ AL,
           const unsigned short* __restrict__ BH, const unsigned short* __restrict__ BL,
           float* __restrict__ E,
           const float* __restrict__ SSp, float* __restrict__ rs,
           unsigned long long* __restrict__ PK,
           int colBaseQ, int colLim, int Ncols, int gx, int nwg) {
    __shared__ short sm[32768];                 // 2 buffers x 4 arrays x [128][32] bf16 = 64KB

    int orig = blockIdx.x;
    int t = threadIdx.x;

    // ---- fused rs + PK-zero prologue (8 blocks x 512 threads = NPOS) ----
    if (orig < 8) {
        int j = (orig << 9) + t;
        int yj = j >> 6, xj = j & 63;
        float s = 0.f;
        #pragma unroll
        for (int kh = 0; kh < 3; ++kh) {
            int ry = reflect_idx(yj + kh);
            #pragma unroll
            for (int kw = 0; kw < 3; ++kw) {
                int p = ry * 64 + reflect_idx(xj + kw);
                #pragma unroll
                for (int part = 0; part < 8; ++part)
                    s += SSp[part * NPOS + p];
            }
        }
        rs[j] = 1.0f / sqrtf(s);
        PK[j] = 0ull;
        asm volatile("s_waitcnt vmcnt(0)" ::: "memory");   // clean counter for STAGE
    }

    int q = nwg >> 3, r = nwg & 7;
    int xcd = orig & 7, rank = orig >> 3;
    int L = (xcd < r ? xcd * (q + 1) : r * (q + 1) + (xcd - r) * q) + rank;
    int by = L / gx, bx = L - by * gx;

    int lane = t & 63, wv = t >> 6;              // 8 waves
    int wr = wv >> 2, wc = wv & 3;               // wave tile: 64 rows x 32 cols
    int bm = by * 128, bn = bx * 128;
    int rowLoc = lane >> 2;                      // 0..15 within a 16-row block
    int kc2 = (((lane & 3) ^ ((lane >> 3) & 3))) << 3;   // swizzled src k-offset (elems)
    int krd = (((lane >> 4) ^ ((lane >> 1) & 3))) << 3;  // swizzled frag-read k-offset

    const unsigned short* mats[4] = {AH, AL, BH, BL};
    const unsigned short* M = mats[wv >> 1];
    int rbase = ((wv >> 1) >= 2 ? colBaseQ + bn : bm) + (wv & 1) * 64;
    const unsigned short* gp[4];
    #pragma unroll
    for (int i = 0; i < 4; ++i) {
        int rr = rbase + i * 16 + rowLoc;
        if (rr > PAD_HW - 1) rr = PAD_HW - 1;
        gp[i] = M + (size_t)rr * C_CH + kc2;
    }
    int ldst = wv * 2048;                        // shorts: wave's half-array base

    auto STAGE = [&](short* base, int koff) {
        #pragma unroll
        for (int i = 0; i < 4; ++i)
            gload16(gp[i] + koff, base + ldst + i * 512);
    };

    f32x4 acc[4][2];
    #pragma unroll
    for (int mt = 0; mt < 4; ++mt)
        #pragma unroll
        for (int nt = 0; nt < 2; ++nt)
            acc[mt][nt] = (f32x4){0.f, 0.f, 0.f, 0.f};

    STAGE(sm, 0);                                // tile 0: 4 loads in flight/wave

    #pragma unroll
    for (int ks = 0; ks < 8; ++ks) {
        short* cb = sm + (ks & 1) * 16384;
        if (ks < 7) {
            STAGE(sm + ((ks + 1) & 1) * 16384, (ks + 1) * 32);   // +4 in flight
            asm volatile("s_waitcnt vmcnt(4)" ::: "memory");     // tile ks landed
        } else {
            asm volatile("s_waitcnt vmcnt(0)" ::: "memory");
        }
        __builtin_amdgcn_s_barrier();
        __builtin_amdgcn_sched_barrier(0);

        short* sAH = cb;
        short* sAL = cb + 4096;
        short* sBH = cb + 8192;
        short* sBL = cb + 12288;
        bf16x8 aH[4], aL[4], bH[2], bL[2];
        #pragma unroll
        for (int mt = 0; mt < 4; ++mt) {
            int off = (wr * 64 + mt * 16 + (lane & 15)) * 32 + krd;
            aH[mt] = *(const bf16x8*)(sAH + off);
            aL[mt] = *(const bf16x8*)(sAL + off);
        }
        #pragma unroll
        for (int nt = 0; nt < 2; ++nt) {
            int off = (wc * 32 + nt * 16 + (lane & 15)) * 32 + krd;
            bH[nt] = *(const bf16x8*)(sBH + off);
            bL[nt] = *(const bf16x8*)(sBL + off);
        }
        __builtin_amdgcn_s_setprio(1);
        #pragma unroll
        for (int mt = 0; mt < 4; ++mt)
            #pragma unroll
            for (int nt = 0; nt < 2; ++nt) {
                f32x4 c = acc[mt][nt];
                c = __builtin_amdgcn_mfma_f32_16x16x32_bf16(aH[mt], bH[nt], c, 0, 0, 0);
                c = __builtin_amdgcn_mfma_f32_16x16x32_bf16(aH[mt], bL[nt], c, 0, 0, 0);
                c = __builtin_amdgcn_mfma_f32_16x16x32_bf16(aL[mt], bH[nt], c, 0, 0, 0);
                acc[mt][nt] = c;
            }
        __builtin_amdgcn_s_setprio(0);

        asm volatile("s_waitcnt lgkmcnt(0)" ::: "memory");
        __builtin_amdgcn_s_barrier();
        __builtin_amdgcn_sched_barrier(0);
    }

    // ---- direct store: padded Ncols makes each 16-lane run a full 64B line ----
    #pragma unroll
    for (int mt = 0; mt < 4; ++mt) {
        int row0 = bm + wr * 64 + mt * 16 + (lane >> 4) * 4;
        #pragma unroll
        for (int nt = 0; nt < 2; ++nt) {
            int col = bn + wc * 32 + nt * 16 + (lane & 15);
            if (col < colLim) {
                #pragma unroll
                for (int r2 = 0; r2 < 4; ++r2) {
                    int row = row0 + r2;
                    if (row < PAD_HW)
                        E[(size_t)row * Ncols + col] = acc[mt][nt][r2];
                }
            }
        }
    }
}

// ---------------- fused 9-tap score + normalize + packed-atomic argmax ----------------
// One u64 per position: (mono(score)<<32)|~j; atomicMax == argmax w/ lowest-j ties.
__global__ void __launch_bounds__(256)
score_argmax(const float* __restrict__ E, const float* __restrict__ rs,
             unsigned long long* __restrict__ PK,
             int g, int R, int Ncols) {
    __shared__ float T[3 * 66 * 68];   // 3 strip buffers, stride 68
    __shared__ float sv[4][64];
    __shared__ int   sj[4][64];

    int bid = blockIdx.x;
    int d = bid % R;                   // diagonal
    int c = bid / R;                   // chunk
    int s0 = c * CHUNK;
    int t = threadIdx.x;
    int xi = t & 63, s2 = t >> 6, xj0 = s2 * 16;

    int u0 = t / 66, v0 = t - u0 * 66; // walk base for e = t + 256*i

    bool valid = false;
    float r[18];

    for (int s = s0; s < s0 + CHUNK; ++s) {
        int yjl = (s + d) & (R - 1);

        if (!valid) {                  // warmup / post-wrap: load 3 strips
            __syncthreads();
            for (int kh = 0; kh < 3; ++kh) {
                float* Tb = T + ((s + kh) % 3) * 4488;
                const float* Eb = E + (size_t)((s + kh) * 66) * Ncols + (yjl + kh) * 66;
                int u = u0, v = v0;
                #pragma unroll
                for (int i = 0; i < 17; ++i) {
                    Tb[u * 68 + v] = Eb[(size_t)u * Ncols + v];
                    v += 58; u += 3; if (v >= 66) { v -= 66; ++u; }
                }
                if (t < 4) Tb[65 * 68 + 62 + t] = Eb[(size_t)65 * Ncols + 62 + t];
            }
            __syncthreads();
            valid = true;
        }

        // prefetch next step's new strip into regs (issue before compute)
        int yjl_next = (s + 1 + d) & (R - 1);
        bool pf = (s + 1 < s0 + CHUNK) && (yjl_next == yjl + 1);
        if (pf) {
            const float* Eb = E + (size_t)((s + 3) * 66) * Ncols + (yjl + 3) * 66;
            int u = u0, v = v0;
            #pragma unroll
            for (int i = 0; i < 17; ++i) {
                r[i] = Eb[(size_t)u * Ncols + v];
                v += 58; u += 3; if (v >= 66) { v -= 66; ++u; }
            }
            if (t < 4) r[17] = Eb[(size_t)65 * Ncols + 62 + t];
        }

        // compute 9-tap scores for this (yi=s, yjl): register row-windows
        float sc[16];
        #pragma unroll
        for (int q2 = 0; q2 < 16; ++q2) sc[q2] = 0.f;
        #pragma unroll
        for (int kh = 0; kh < 3; ++kh) {
            const float* Tk = T + ((s + kh) % 3) * 4488;
            #pragma unroll
            for (int kw = 0; kw < 3; ++kw) {
                const float* rp = Tk + (xi + kw) * 68 + xj0;
                float rr[18];
                *(float4*)&rr[0]  = *(const float4*)&rp[0];
                *(float4*)&rr[4]  = *(const float4*)&rp[4];
                *(float4*)&rr[8]  = *(const float4*)&rp[8];
                *(float4*)&rr[12] = *(const float4*)&rp[12];
                if (kw > 0) *(float2*)&rr[16] = *(const float2*)&rp[16];
                #pragma unroll
                for (int q2 = 0; q2 < 16; ++q2) sc[q2] += rr[kw + q2];
            }
        }

        // normalize + local argmax over this thread's 16 xj
        int jbase = ((g * R + yjl) << 6) + xj0;
        float bv = -INFINITY; int bj = 0;
        #pragma unroll
        for (int q2 = 0; q2 < 16; ++q2) {
            float v = sc[q2] * rs[jbase + q2];
            if (v > bv) { bv = v; bj = jbase + q2; }
        }
        // s2-reduction in LDS, then ONE packed atomicMax per position
        sv[s2][xi] = bv; sj[s2][xi] = bj;
        __syncthreads();
        if (s2 == 0) {
            #pragma unroll
            for (int u = 1; u < 4; ++u) {
                float ov = sv[u][xi]; int oj = sj[u][xi];
                if (ov > bv || (ov == bv && oj < bj)) { bv = ov; bj = oj; }
            }
            unsigned long long pk =
                ((unsigned long long)fmono(bv) << 32) | (unsigned int)(~bj);
            atomicMax(PK + (s << 6) + xi, pk);
        }

        if (pf) {                      // drain prefetch into freed buffer
            __syncthreads();
            float* Tb = T + ((s + 3) % 3) * 4488;
            int u = u0, v = v0;
            #pragma unroll
            for (int i = 0; i < 17; ++i) {
                Tb[u * 68 + v] = r[i];
                v += 58; u += 3; if (v >= 66) { v -= 66; ++u; }
            }
            if (t < 4) Tb[65 * 68 + 62 + t] = r[17];
            __syncthreads();
        } else {
            valid = false;
        }
    }
}

// ---------------- build masked matrices as split-bf16 H/L [c][4096] ----------------
// Also zeroes the loss accumulator (replaces the d_out memset node; loss runs
// two nodes later so the zero is globally visible by then).
__global__ void __launch_bounds__(256)
build_xy_kernel(const float* __restrict__ input_fm,
                const float* __restrict__ style,
                const float* __restrict__ mask,
                const unsigned long long* __restrict__ PK,
                unsigned short* __restrict__ XmH, unsigned short* __restrict__ XmL,
                unsigned short* __restrict__ YmH, unsigned short* __restrict__ YmL,
                float* __restrict__ out) {
    if (blockIdx.x == 0 && threadIdx.x == 0) *out = 0.0f;
    int e4 = blockIdx.x * 256 + threadIdx.x;    // grid 1024: C_CH*NPOS/4
    int c = e4 >> 10;
    int i0 = (e4 & 1023) << 2;
    int base = (c << 12) + i0;
    float4 inv = *(const float4*)&input_fm[base];
    float4 mv  = *(const float4*)&mask[i0];
    const float* sc = style + ((size_t)c << 12);
    float x[4], y[4];
    x[0] = inv.x * mv.x; x[1] = inv.y * mv.y; x[2] = inv.z * mv.z; x[3] = inv.w * mv.w;
    float mvv[4] = {mv.x, mv.y, mv.z, mv.w};
    #pragma unroll
    for (int k = 0; k < 4; ++k) {
        unsigned long long pk = PK[i0 + k];
        int j = (int)(~(unsigned int)(pk & 0xffffffffu));
        y[k] = sc[j] * mvv[k];
    }
    ushort4 xh, xl, yh, yl;
    #pragma unroll
    for (int j = 0; j < 4; ++j) {
        unsigned short h = f2bf(x[j]);
        float hf = __uint_as_float((unsigned int)h << 16);
        ((unsigned short*)&xh)[j] = h;
        ((unsigned short*)&xl)[j] = f2bf(x[j] - hf);
        unsigned short h2 = f2bf(y[j]);
        float hf2 = __uint_as_float((unsigned int)h2 << 16);
        ((unsigned short*)&yh)[j] = h2;
        ((unsigned short*)&yl)[j] = f2bf(y[j] - hf2);
    }
    *(ushort4*)&XmH[base] = xh;
    *(ushort4*)&XmL[base] = xl;
    *(ushort4*)&YmH[base] = yh;
    *(ushort4*)&YmL[base] = yl;
}

// ---------------- MFMA dual-gram diff: 64x64 tiles x 32 pos-slices ----------------
__global__ void __launch_bounds__(256)
gram_mfma(const unsigned short* __restrict__ XH, const unsigned short* __restrict__ XL,
          const unsigned short* __restrict__ YH, const unsigned short* __restrict__ YL,
          float* __restrict__ Dpart) {
    __shared__ short sm[32768];   // 2 buf x 8 arrays x [64][32] bf16 = 64 KB
    const int PI[10] = {0,0,0,0,1,1,1,2,2,3};
    const int PJ[10] = {0,1,2,3,1,2,3,2,3,3};
    int pr = blockIdx.x, sl = blockIdx.y;
    int ti = PI[pr], tj = PJ[pr];
    int c0 = ti * 64, d0 = tj * 64;
    int t = threadIdx.x, lane = t & 63, wv = t >> 6;
    int wr = wv >> 1, wc = wv & 1;
    int rowLoc = wv * 16 + (lane >> 2);                  // 0..63
    int kc2 = (((lane & 3) ^ ((lane >> 3) & 3))) << 3;
    int krd = (((lane >> 4) ^ ((lane >> 1) & 3))) << 3;
    int posBase = sl * 128 + kc2;

    const unsigned short* g0 = XH + (size_t)(c0 + rowLoc) * NPOS + posBase;
    const unsigned short* g1 = XL + (size_t)(c0 + rowLoc) * NPOS + posBase;
    const unsigned short* g2 = XH + (size_t)(d0 + rowLoc) * NPOS + posBase;
    const unsigned short* g3 = XL + (size_t)(d0 + rowLoc) * NPOS + posBase;
    const unsigned short* g4 = YH + (size_t)(c0 + rowLoc) * NPOS + posBase;
    const unsigned short* g5 = YL + (size_t)(c0 + rowLoc) * NPOS + posBase;
    const unsigned short* g6 = YH + (size_t)(d0 + rowLoc) * NPOS + posBase;
    const unsigned short* g7 = YL + (size_t)(d0 + rowLoc) * NPOS + posBase;
    int lb = wv * 512;

    auto STAGE = [&](short* base, int koff) {
        gload16(g0 + koff, base + lb);
        gload16(g1 + koff, base + 2048 + lb);
        gload16(g2 + koff, base + 4096 + lb);
        gload16(g3 + koff, base + 6144 + lb);
        gload16(g4 + koff, base + 8192 + lb);
        gload16(g5 + koff, base + 10240 + lb);
        gload16(g6 + koff, base + 12288 + lb);
        gload16(g7 + koff, base + 14336 + lb);
    };

    f32x4 aX[2][2], aY[2][2];
    #pragma unroll
    for (int mt = 0; mt < 2; ++mt)
        #pragma unroll
        for (int nt = 0; nt < 2; ++nt) {
            aX[mt][nt] = (f32x4){0.f, 0.f, 0.f, 0.f};
            aY[mt][nt] = (f32x4){0.f, 0.f, 0.f, 0.f};
        }

    STAGE(sm, 0);

    #pragma unroll
    for (int ks = 0; ks < 4; ++ks) {
        short* cb = sm + (ks & 1) * 16384;
        if (ks < 3) {
            STAGE(sm + ((ks + 1) & 1) * 16384, (ks + 1) * 32);
            asm volatile("s_waitcnt vmcnt(8)" ::: "memory");
        } else {
            asm volatile("s_waitcnt vmcnt(0)" ::: "memory");
        }
        __builtin_amdgcn_s_barrier();
        __builtin_amdgcn_sched_barrier(0);

        bf16x8 xcH[2], xcL[2], xdH[2], xdL[2], ycH[2], ycL[2], ydH[2], ydL[2];
        #pragma unroll
        for (int mt = 0; mt < 2; ++mt) {
            int off = (wr * 32 + mt * 16 + (lane & 15)) * 32 + krd;
            xcH[mt] = *(const bf16x8*)(cb + off);
            xcL[mt] = *(const bf16x8*)(cb + 2048 + off);
            ycH[mt] = *(const bf16x8*)(cb + 8192 + off);
            ycL[mt] = *(const bf16x8*)(cb + 10240 + off);
        }
        #pragma unroll
        for (int nt = 0; nt < 2; ++nt) {
            int off = (wc * 32 + nt * 16 + (lane & 15)) * 32 + krd;
            xdH[nt] = *(const bf16x8*)(cb + 4096 + off);
            xdL[nt] = *(const bf16x8*)(cb + 6144 + off);
            ydH[nt] = *(const bf16x8*)(cb + 12288 + off);
            ydL[nt] = *(const bf16x8*)(cb + 14336 + off);
        }
        __builtin_amdgcn_s_setprio(1);
        #pragma unroll
        for (int mt = 0; mt < 2; ++mt)
            #pragma unroll
            for (int nt = 0; nt < 2; ++nt) {
                f32x4 cx = aX[mt][nt];
                cx = __builtin_amdgcn_mfma_f32_16x16x32_bf16(xcH[mt], xdH[nt], cx, 0, 0, 0);
                cx = __builtin_amdgcn_mfma_f32_16x16x32_bf16(xcH[mt], xdL[nt], cx, 0, 0, 0);
                cx = __builtin_amdgcn_mfma_f32_16x16x32_bf16(xcL[mt], xdH[nt], cx, 0, 0, 0);
                aX[mt][nt] = cx;
                f32x4 cy = aY[mt][nt];
                cy = __builtin_amdgcn_mfma_f32_16x16x32_bf16(ycH[mt], ydH[nt], cy, 0, 0, 0);
                cy = __builtin_amdgcn_mfma_f32_16x16x32_bf16(ycH[mt], ydL[nt], cy, 0, 0, 0);
                cy = __builtin_amdgcn_mfma_f32_16x16x32_bf16(ycL[mt], ydH[nt], cy, 0, 0, 0);
                aY[mt][nt] = cy;
            }
        __builtin_amdgcn_s_setprio(0);

        asm volatile("s_waitcnt lgkmcnt(0)" ::: "memory");
        __builtin_amdgcn_s_barrier();
        __builtin_amdgcn_sched_barrier(0);
    }

    // ---- coalesced epilogue: 64x64 diff tile via LDS (stride 68), float4 out ----
    float* fs = (float*)sm;                      // 64*68*4 = 17.4KB < 64KB
    #pragma unroll
    for (int mt = 0; mt < 2; ++mt) {
        int rl = wr * 32 + mt * 16 + ((lane >> 4) << 2);
        #pragma unroll
        for (int nt = 0; nt < 2; ++nt) {
            int cl = wc * 32 + nt * 16 + (lane & 15);
            #pragma unroll
            for (int r2 = 0; r2 < 4; ++r2)
                fs[(rl + r2) * 68 + cl] = aX[mt][nt][r2] - aY[mt][nt][r2];
        }
    }
    __syncthreads();
    float* Db = Dpart + ((size_t)sl * 10 + pr) * 4096;
    int rr0 = t >> 4;              // 0..15
    int cc0 = (t & 15) << 2;       // 0..60
    #pragma unroll
    for (int i = 0; i < 4; ++i) {
        int rr = rr0 + (i << 4);
        *(float4*)&Db[rr * 64 + cc0] = *(const float4*)&fs[rr * 68 + cc0];
    }
}

// ---------------- final loss (mask-sum fused; upper-tile iteration, off-diag x2) ----------------
__global__ void __launch_bounds__(256)
loss_kernel(const float* __restrict__ Dpart, const float* __restrict__ mask,
            float* __restrict__ out) {
    const int PI[10] = {0,0,0,0,1,1,1,2,2,3};
    const int PJ[10] = {0,1,2,3,1,2,3,2,3,3};
    __shared__ float red[4];
    int tid = threadIdx.x;

    float ms = 0.f;
    for (int i = tid; i < NPOS; i += 256) ms += mask[i];
    #pragma unroll
    for (int o = 32; o >= 1; o >>= 1) ms += __shfl_down(ms, o, 64);
    if ((tid & 63) == 0) red[tid >> 6] = ms;
    __syncthreads();
    float msum = 256.0f * (red[0] + red[1] + red[2] + red[3]);
    __syncthreads();                    // red[] reused below

    int e2 = blockIdx.x * 256 + tid;    // grid 160: 10 tiles x 4096
    int tt = e2 >> 12;                  // uniform within block
    int ei = e2 & 4095;
    float d = 0.f;
    #pragma unroll
    for (int s = 0; s < GSLICE; ++s)
        d += Dpart[(size_t)(s * 10 + tt) * 4096 + ei];
    float inv = 1.0f / msum;
    float v = d * inv;
    float w = (PI[tt] != PJ[tt]) ? 2.0f : 1.0f;
    float ls = w * v * v;
    #pragma unroll
    for (int o = 32; o >= 1; o >>= 1) ls += __shfl_down(ls, o, 64);
    if ((tid & 63) == 0) red[tid >> 6] = ls;
    __syncthreads();
    if (tid == 0)
        atomicAdd(out, (red[0] + red[1] + red[2] + red[3]) * (100.0f / 65536.0f));
}

extern "C" void kernel_launch(void* const* d_in, const int* in_sizes, int n_in,
                              void* d_out, int out_size, void* d_ws, size_t ws_size,
                              hipStream_t stream) {
    (void)in_sizes; (void)n_in; (void)out_size;
    const float* content = (const float*)d_in[0];
    const float* style   = (const float*)d_in[1];
    const float* input   = (const float*)d_in[2];
    const float* mask    = (const float*)d_in[3];
    float* out = (float*)d_out;

    auto alignup = [](size_t b) { return (b + 255) & ~size_t(255); };

    size_t szT   = alignup((size_t)PAD_HW * C_CH * 2);
    size_t szSS  = alignup((size_t)8 * NPOS * 4);
    size_t szRS  = alignup((size_t)NPOS * 4);
    size_t szPK  = alignup((size_t)NPOS * 8);
    size_t szXYb = alignup((size_t)C_CH * NPOS * 2);    // bf16 H/L arrays
    size_t szDp  = alignup((size_t)GSLICE * 10 * 4096 * 4);
    size_t fixed = 4 * szT + szSS + szRS + szPK + 4 * szXYb + szDp;

    // E row stride padded to a multiple of 16 floats (64B) -> full-line stores
    auto padcols = [](int c) { return (c + 15) & ~15; };

    auto needE = [&](int NG) {
        size_t Nc = (size_t)padcols((64 / NG + 2) * PAD_W);
        return fixed + alignup((size_t)PAD_HW * Nc * 4) + 4096;
    };
    // R6 lesson: NG=2 regressed (launch serialization + tails). NG=1 is best.
    int NG = 8;
    if      (ws_size >= needE(1)) NG = 1;
    else if (ws_size >= needE(2)) NG = 2;
    else if (ws_size >= needE(4)) NG = 4;
    int R = 64 / NG;
    int colLim = (R + 2) * PAD_W;          // real columns
    int Ncols = padcols(colLim);           // padded row stride

    char* ws = (char*)d_ws;
    size_t off = 0;
    auto alloc = [&](size_t bytes) { void* p = ws + off; off += alignup(bytes); return p; };

    unsigned short* cTH = (unsigned short*)alloc((size_t)PAD_HW * C_CH * 2);
    unsigned short* cTL = (unsigned short*)alloc((size_t)PAD_HW * C_CH * 2);
    unsigned short* sTH = (unsigned short*)alloc((size_t)PAD_HW * C_CH * 2);
    unsigned short* sTL = (unsigned short*)alloc((size_t)PAD_HW * C_CH * 2);
    float* SSp   = (float*)alloc((size_t)8 * NPOS * 4);
    float* rs    = (float*)alloc((size_t)NPOS * 4);
    unsigned long long* PK = (unsigned long long*)alloc((size_t)NPOS * 8);
    unsigned short* XmH = (unsigned short*)alloc((size_t)C_CH * NPOS * 2);
    unsigned short* XmL = (unsigned short*)alloc((size_t)C_CH * NPOS * 2);
    unsigned short* YmH = (unsigned short*)alloc((size_t)C_CH * NPOS * 2);
    unsigned short* YmL = (unsigned short*)alloc((size_t)C_CH * NPOS * 2);
    float* Dpart = (float*)alloc((size_t)GSLICE * 10 * 4096 * 4);
    float* E     = (float*)alloc((size_t)PAD_HW * Ncols * 4);

    split_kernel<<<dim3(69, 4, 3), 256, 0, stream>>>(content, style, cTH, cTL, sTH, sTL, SSp);

    int gx = (colLim + 127) / 128;
    int gy = (PAD_HW + 127) / 128;
    int nwg = gx * gy;
    for (int g = 0; g < NG; ++g) {
        int colBaseQ = g * R * PAD_W;
        egemm_mfma<<<nwg, 512, 0, stream>>>(cTH, cTL, sTH, sTL, E, SSp, rs, PK,
                                            colBaseQ, colLim, Ncols, gx, nwg);
        score_argmax<<<R * (64 / CHUNK), 256, 0, stream>>>(E, rs, PK, g, R, Ncols);
    }
    build_xy_kernel<<<1024, 256, 0, stream>>>(input, style, mask, PK, XmH, XmL, YmH, YmL, out);
    gram_mfma<<<dim3(10, GSLICE), 256, 0, stream>>>(XmH, XmL, YmH, YmL, Dpart);
    loss_kernel<<<160, 256, 0, stream>>>(Dpart, mask, out);
}

// Round 10
// 101.635 us; speedup vs baseline: 1.5617x; 1.0748x over previous
//
#include <hip/hip_runtime.h>
#include <math.h>

#define C_CH 256
#define NPOS 4096              // 64*64 spatial positions
#define GSLICE 32              // gram position-axis slices (128 pos each)
#define CHUNK 8                // diagonal steps per score block
#define ENC 4112               // E raw row stride (floats): 4096+16, 64B mult, non-pow2

typedef __bf16 bf16x8 __attribute__((ext_vector_type(8)));
typedef float  f32x4  __attribute__((ext_vector_type(4)));

__device__ __forceinline__ int reflect_idx(int p) {
    int s = p - 1;
    if (s < 0) s = -s;
    if (s > 63) s = 126 - s;
    return s;
}

__device__ __forceinline__ unsigned short f2bf(float x) {
    unsigned int u = __float_as_uint(x);
    unsigned int r = u + 0x7fffu + ((u >> 16) & 1u);
    return (unsigned short)(r >> 16);
}

// monotone f32 -> u32 map: a < b  <=>  mono(a) < mono(b)
__device__ __forceinline__ unsigned int fmono(float f) {
    unsigned int b = __float_as_uint(f);
    return (b & 0x80000000u) ? ~b : (b | 0x80000000u);
}

// async global->LDS, 16B per lane; LDS dest = wave-uniform base + lane*16
__device__ __forceinline__ void gload16(const void* g, void* l) {
    __builtin_amdgcn_global_load_lds(
        (const __attribute__((address_space(1))) unsigned int*)g,
        (__attribute__((address_space(3))) unsigned int*)l, 16, 0, 0);
}

// ---------------- raw transpose + hi/lo bf16 split (z<2) + style sq-sums (z==2) ----------------
// R10: E is now raw-only (4096x4096); the reflect gather moved into score's
// strip loader, so split is a pure [c][pos] -> [pos][c] transpose.
__global__ void __launch_bounds__(256)
split_kernel(const float* __restrict__ content, const float* __restrict__ style,
             unsigned short* __restrict__ cTH, unsigned short* __restrict__ cTL,
             unsigned short* __restrict__ sTH, unsigned short* __restrict__ sTL,
             float* __restrict__ SSp) {
    __shared__ float tile[64][65];
    int t = threadIdx.x;

    if (blockIdx.z == 2) {             // fused ssp: 128 logical blocks
        int bi = blockIdx.y * 64 + blockIdx.x;
        if (bi >= 128) return;
        int pos = ((bi & 15) << 8) + t;
        int cg = bi >> 4;              // 0..7
        float s = 0.f;
        for (int c = cg * 32; c < cg * 32 + 32; ++c) {
            float v = style[(size_t)c * NPOS + pos];
            s += v * v;
        }
        SSp[cg * NPOS + pos] = s;
        return;
    }

    const float* src = blockIdx.z ? style : content;
    unsigned short* oH = blockIdx.z ? sTH : cTH;
    unsigned short* oL = blockIdx.z ? sTL : cTL;
    int p0 = blockIdx.x * 64, c0 = blockIdx.y * 64;
    int posl = t & 63;
    int p = p0 + posl;
    #pragma unroll
    for (int r = 0; r < 16; ++r) {
        int cl = (t >> 6) + r * 4;
        tile[posl][cl] = src[(size_t)(c0 + cl) * NPOS + p];
    }
    __syncthreads();
    int cl2 = t & 63;
    #pragma unroll
    for (int r = 0; r < 16; ++r) {
        int pl = (t >> 6) + r * 4;
        int pg = p0 + pl;
        float x = tile[pl][cl2];
        unsigned short h = f2bf(x);
        float hf = __uint_as_float((unsigned int)h << 16);
        unsigned short l = f2bf(x - hf);
        oH[(size_t)pg * C_CH + c0 + cl2] = h;
        oL[(size_t)pg * C_CH + c0 + cl2] = l;
    }
}

// ---------------- split-bf16 MFMA E-GEMM: 8-wave blocks, raw 4096x4096 ----------------
// R10: M=N=4096 exactly -> 1024 blocks = 2.0 full block-waves (no tail), no
// row clamps, -12% MFMA vs padded. rs+PK prologue in blocks orig<8 (R9).
__global__ void __launch_bounds__(512, 4)
egemm_mfma(const unsigned short* __restrict__ AH, const unsigned short* __restrict__ AL,
           const unsigned short* __restrict__ BH, const unsigned short* __restrict__ BL,
           float* __restrict__ E,
           const float* __restrict__ SSp, float* __restrict__ rs,
           unsigned long long* __restrict__ PK, int nwg) {
    __shared__ short sm[32768];                 // 2 buffers x 4 arrays x [128][32] bf16 = 64KB

    int orig = blockIdx.x;
    int t = threadIdx.x;

    // ---- fused rs + PK-zero prologue (8 blocks x 512 threads = NPOS) ----
    if (orig < 8) {
        int j = (orig << 9) + t;
        int yj = j >> 6, xj = j & 63;
        float s = 0.f;
        #pragma unroll
        for (int kh = 0; kh < 3; ++kh) {
            int ry = reflect_idx(yj + kh);
            #pragma unroll
            for (int kw = 0; kw < 3; ++kw) {
                int p = ry * 64 + reflect_idx(xj + kw);
                #pragma unroll
                for (int part = 0; part < 8; ++part)
                    s += SSp[part * NPOS + p];
            }
        }
        rs[j] = 1.0f / sqrtf(s);
        PK[j] = 0ull;
        asm volatile("s_waitcnt vmcnt(0)" ::: "memory");   // clean counter for STAGE
    }

    int q = nwg >> 3;
    int xcd = orig & 7, rank = orig >> 3;
    int L = xcd * q + rank;                      // nwg=1024: bijective
    int by = L >> 5, bx = L & 31;                // gx = 32

    int lane = t & 63, wv = t >> 6;              // 8 waves
    int wr = wv >> 2, wc = wv & 3;               // wave tile: 64 rows x 32 cols
    int bm = by * 128, bn = bx * 128;
    int rowLoc = lane >> 2;                      // 0..15 within a 16-row block
    int kc2 = (((lane & 3) ^ ((lane >> 3) & 3))) << 3;   // swizzled src k-offset (elems)
    int krd = (((lane >> 4) ^ ((lane >> 1) & 3))) << 3;  // swizzled frag-read k-offset

    const unsigned short* mats[4] = {AH, AL, BH, BL};
    const unsigned short* M = mats[wv >> 1];
    int rbase = ((wv >> 1) >= 2 ? bn : bm) + (wv & 1) * 64;
    const unsigned short* gp[4];
    #pragma unroll
    for (int i = 0; i < 4; ++i)
        gp[i] = M + (size_t)(rbase + i * 16 + rowLoc) * C_CH + kc2;
    int ldst = wv * 2048;                        // shorts: wave's half-array base

    auto STAGE = [&](short* base, int koff) {
        #pragma unroll
        for (int i = 0; i < 4; ++i)
            gload16(gp[i] + koff, base + ldst + i * 512);
    };

    f32x4 acc[4][2];
    #pragma unroll
    for (int mt = 0; mt < 4; ++mt)
        #pragma unroll
        for (int nt = 0; nt < 2; ++nt)
            acc[mt][nt] = (f32x4){0.f, 0.f, 0.f, 0.f};

    STAGE(sm, 0);                                // tile 0: 4 loads in flight/wave

    #pragma unroll
    for (int ks = 0; ks < 8; ++ks) {
        short* cb = sm + (ks & 1) * 16384;
        if (ks < 7) {
            STAGE(sm + ((ks + 1) & 1) * 16384, (ks + 1) * 32);   // +4 in flight
            asm volatile("s_waitcnt vmcnt(4)" ::: "memory");     // tile ks landed
        } else {
            asm volatile("s_waitcnt vmcnt(0)" ::: "memory");
        }
        __builtin_amdgcn_s_barrier();
        __builtin_amdgcn_sched_barrier(0);

        short* sAH = cb;
        short* sAL = cb + 4096;
        short* sBH = cb + 8192;
        short* sBL = cb + 12288;
        bf16x8 aH[4], aL[4], bH[2], bL[2];
        #pragma unroll
        for (int mt = 0; mt < 4; ++mt) {
            int off = (wr * 64 + mt * 16 + (lane & 15)) * 32 + krd;
            aH[mt] = *(const bf16x8*)(sAH + off);
            aL[mt] = *(const bf16x8*)(sAL + off);
        }
        #pragma unroll
        for (int nt = 0; nt < 2; ++nt) {
            int off = (wc * 32 + nt * 16 + (lane & 15)) * 32 + krd;
            bH[nt] = *(const bf16x8*)(sBH + off);
            bL[nt] = *(const bf16x8*)(sBL + off);
        }
        __builtin_amdgcn_s_setprio(1);
        #pragma unroll
        for (int mt = 0; mt < 4; ++mt)
            #pragma unroll
            for (int nt = 0; nt < 2; ++nt) {
                f32x4 c = acc[mt][nt];
                c = __builtin_amdgcn_mfma_f32_16x16x32_bf16(aH[mt], bH[nt], c, 0, 0, 0);
                c = __builtin_amdgcn_mfma_f32_16x16x32_bf16(aH[mt], bL[nt], c, 0, 0, 0);
                c = __builtin_amdgcn_mfma_f32_16x16x32_bf16(aL[mt], bH[nt], c, 0, 0, 0);
                acc[mt][nt] = c;
            }
        __builtin_amdgcn_s_setprio(0);

        asm volatile("s_waitcnt lgkmcnt(0)" ::: "memory");
        __builtin_amdgcn_s_barrier();
        __builtin_amdgcn_sched_barrier(0);
    }

    // ---- direct store: full 64B lines, no guards (exact 4096 tiling) ----
    #pragma unroll
    for (int mt = 0; mt < 4; ++mt) {
        int row0 = bm + wr * 64 + mt * 16 + (lane >> 4) * 4;
        #pragma unroll
        for (int nt = 0; nt < 2; ++nt) {
            int col = bn + wc * 32 + nt * 16 + (lane & 15);
            #pragma unroll
            for (int r2 = 0; r2 < 4; ++r2)
                E[(size_t)(row0 + r2) * ENC + col] = acc[mt][nt][r2];
        }
    }
}

// ---------------- fused 9-tap score + normalize + packed-atomic argmax ----------------
// R10: strips are loaded from RAW E; reflect edges replicated in-register in
// the same phase (each thread writes its raw values to every padded slot that
// maps to them). T keeps the padded [66][68] layout -> taps unchanged.
__global__ void __launch_bounds__(256)
score_argmax(const float* __restrict__ E, const float* __restrict__ rs,
             unsigned long long* __restrict__ PK) {
    __shared__ float T[3 * 66 * 68];   // 3 strip buffers, stride 68
    __shared__ float sv[4][64];
    __shared__ int   sj[4][64];

    int bid = blockIdx.x;
    int d = bid & 63;                  // diagonal (R=64)
    int c = bid >> 6;                  // chunk
    int s0 = c * CHUNK;
    int t = threadIdx.x;
    int xi = t & 63, s2 = t >> 6, xj0 = s2 * 16;
    int rr = t >> 2;                   // raw content px row 0..63
    int j0 = (t & 3) << 4;             // raw style px col base {0,16,32,48}

    auto STORESTRIP = [&](float* Tb, const float* w) {
        float* row = Tb + (rr + 1) * 68;
        #pragma unroll
        for (int q2 = 0; q2 < 16; ++q2) row[1 + j0 + q2] = w[q2];
        if (j0 == 0)  row[0]  = w[1];      // padded v=0  -> raw 1
        if (j0 == 48) row[65] = w[14];     // padded v=65 -> raw 62
        if (rr == 1 || rr == 62) {         // padded u=0 -> raw 1, u=65 -> raw 62
            float* erow = Tb + (rr == 1 ? 0 : 65) * 68;
            #pragma unroll
            for (int q2 = 0; q2 < 16; ++q2) erow[1 + j0 + q2] = w[q2];
            if (j0 == 0)  erow[0]  = w[1];
            if (j0 == 48) erow[65] = w[14];
        }
    };
    auto LOADSTRIP = [&](float* Tb, int cy, int sy) {
        int cyr = reflect_idx(cy), syr = reflect_idx(sy);
        const float* Eb = E + (size_t)(cyr * 64 + rr) * ENC + syr * 64 + j0;
        float w[16];
        *(float4*)&w[0]  = *(const float4*)&Eb[0];
        *(float4*)&w[4]  = *(const float4*)&Eb[4];
        *(float4*)&w[8]  = *(const float4*)&Eb[8];
        *(float4*)&w[12] = *(const float4*)&Eb[12];
        STORESTRIP(Tb, w);
    };

    bool valid = false;
    float pfv[16];

    for (int s = s0; s < s0 + CHUNK; ++s) {
        int yjl = (s + d) & 63;

        if (!valid) {                  // warmup / post-wrap: load 3 strips
            __syncthreads();
            for (int kh = 0; kh < 3; ++kh)
                LOADSTRIP(T + ((s + kh) % 3) * 4488, s + kh, yjl + kh);
            __syncthreads();
            valid = true;
        }

        // prefetch next step's new strip into regs (issue before compute)
        int yjl_next = (s + 1 + d) & 63;
        bool pf = (s + 1 < s0 + CHUNK) && (yjl_next == yjl + 1);
        if (pf) {
            int cyr = reflect_idx(s + 3), syr = reflect_idx(yjl + 3);
            const float* Eb = E + (size_t)(cyr * 64 + rr) * ENC + syr * 64 + j0;
            *(float4*)&pfv[0]  = *(const float4*)&Eb[0];
            *(float4*)&pfv[4]  = *(const float4*)&Eb[4];
            *(float4*)&pfv[8]  = *(const float4*)&Eb[8];
            *(float4*)&pfv[12] = *(const float4*)&Eb[12];
        }

        // compute 9-tap scores for this (yi=s, yjl): register row-windows
        float sc[16];
        #pragma unroll
        for (int q2 = 0; q2 < 16; ++q2) sc[q2] = 0.f;
        #pragma unroll
        for (int kh = 0; kh < 3; ++kh) {
            const float* Tk = T + ((s + kh) % 3) * 4488;
            #pragma unroll
            for (int kw = 0; kw < 3; ++kw) {
                const float* rp = Tk + (xi + kw) * 68 + xj0;
                float rw[18];
                *(float4*)&rw[0]  = *(const float4*)&rp[0];
                *(float4*)&rw[4]  = *(const float4*)&rp[4];
                *(float4*)&rw[8]  = *(const float4*)&rp[8];
                *(float4*)&rw[12] = *(const float4*)&rp[12];
                if (kw > 0) *(float2*)&rw[16] = *(const float2*)&rp[16];
                #pragma unroll
                for (int q2 = 0; q2 < 16; ++q2) sc[q2] += rw[kw + q2];
            }
        }

        // normalize + local argmax over this thread's 16 xj
        int jbase = (yjl << 6) + xj0;
        float bv = -INFINITY; int bj = 0;
        #pragma unroll
        for (int q2 = 0; q2 < 16; ++q2) {
            float v = sc[q2] * rs[jbase + q2];
            if (v > bv) { bv = v; bj = jbase + q2; }
        }
        // s2-reduction in LDS, then ONE packed atomicMax per position
        sv[s2][xi] = bv; sj[s2][xi] = bj;
        __syncthreads();
        if (s2 == 0) {
            #pragma unroll
            for (int u = 1; u < 4; ++u) {
                float ov = sv[u][xi]; int oj = sj[u][xi];
                if (ov > bv || (ov == bv && oj < bj)) { bv = ov; bj = oj; }
            }
            unsigned long long pk =
                ((unsigned long long)fmono(bv) << 32) | (unsigned int)(~bj);
            atomicMax(PK + (s << 6) + xi, pk);
        }

        if (pf) {                      // drain prefetch into freed buffer
            __syncthreads();
            STORESTRIP(T + ((s + 3) % 3) * 4488, pfv);
            __syncthreads();
        } else {
            valid = false;
        }
    }
}

// ---------------- build masked matrices as split-bf16 H/L [c][4096] ----------------
// Also zeroes the loss accumulator (replaces the d_out memset node).
__global__ void __launch_bounds__(256)
build_xy_kernel(const float* __restrict__ input_fm,
                const float* __restrict__ style,
                const float* __restrict__ mask,
                const unsigned long long* __restrict__ PK,
                unsigned short* __restrict__ XmH, unsigned short* __restrict__ XmL,
                unsigned short* __restrict__ YmH, unsigned short* __restrict__ YmL,
                float* __restrict__ out) {
    if (blockIdx.x == 0 && threadIdx.x == 0) *out = 0.0f;
    int e4 = blockIdx.x * 256 + threadIdx.x;    // grid 1024: C_CH*NPOS/4
    int c = e4 >> 10;
    int i0 = (e4 & 1023) << 2;
    int base = (c << 12) + i0;
    float4 inv = *(const float4*)&input_fm[base];
    float4 mv  = *(const float4*)&mask[i0];
    const float* sc = style + ((size_t)c << 12);
    float x[4], y[4];
    x[0] = inv.x * mv.x; x[1] = inv.y * mv.y; x[2] = inv.z * mv.z; x[3] = inv.w * mv.w;
    float mvv[4] = {mv.x, mv.y, mv.z, mv.w};
    #pragma unroll
    for (int k = 0; k < 4; ++k) {
        unsigned long long pk = PK[i0 + k];
        int j = (int)(~(unsigned int)(pk & 0xffffffffu));
        y[k] = sc[j] * mvv[k];
    }
    ushort4 xh, xl, yh, yl;
    #pragma unroll
    for (int j = 0; j < 4; ++j) {
        unsigned short h = f2bf(x[j]);
        float hf = __uint_as_float((unsigned int)h << 16);
        ((unsigned short*)&xh)[j] = h;
        ((unsigned short*)&xl)[j] = f2bf(x[j] - hf);
        unsigned short h2 = f2bf(y[j]);
        float hf2 = __uint_as_float((unsigned int)h2 << 16);
        ((unsigned short*)&yh)[j] = h2;
        ((unsigned short*)&yl)[j] = f2bf(y[j] - hf2);
    }
    *(ushort4*)&XmH[base] = xh;
    *(ushort4*)&XmL[base] = xl;
    *(ushort4*)&YmH[base] = yh;
    *(ushort4*)&YmL[base] = yl;
}

// ---------------- MFMA dual-gram diff: 64x64 tiles x 32 pos-slices ----------------
__global__ void __launch_bounds__(256)
gram_mfma(const unsigned short* __restrict__ XH, const unsigned short* __restrict__ XL,
          const unsigned short* __restrict__ YH, const unsigned short* __restrict__ YL,
          float* __restrict__ Dpart) {
    __shared__ short sm[32768];   // 2 buf x 8 arrays x [64][32] bf16 = 64 KB
    const int PI[10] = {0,0,0,0,1,1,1,2,2,3};
    const int PJ[10] = {0,1,2,3,1,2,3,2,3,3};
    int pr = blockIdx.x, sl = blockIdx.y;
    int ti = PI[pr], tj = PJ[pr];
    int c0 = ti * 64, d0 = tj * 64;
    int t = threadIdx.x, lane = t & 63, wv = t >> 6;
    int wr = wv >> 1, wc = wv & 1;
    int rowLoc = wv * 16 + (lane >> 2);                  // 0..63
    int kc2 = (((lane & 3) ^ ((lane >> 3) & 3))) << 3;
    int krd = (((lane >> 4) ^ ((lane >> 1) & 3))) << 3;
    int posBase = sl * 128 + kc2;

    const unsigned short* g0 = XH + (size_t)(c0 + rowLoc) * NPOS + posBase;
    const unsigned short* g1 = XL + (size_t)(c0 + rowLoc) * NPOS + posBase;
    const unsigned short* g2 = XH + (size_t)(d0 + rowLoc) * NPOS + posBase;
    const unsigned short* g3 = XL + (size_t)(d0 + rowLoc) * NPOS + posBase;
    const unsigned short* g4 = YH + (size_t)(c0 + rowLoc) * NPOS + posBase;
    const unsigned short* g5 = YL + (size_t)(c0 + rowLoc) * NPOS + posBase;
    const unsigned short* g6 = YH + (size_t)(d0 + rowLoc) * NPOS + posBase;
    const unsigned short* g7 = YL + (size_t)(d0 + rowLoc) * NPOS + posBase;
    int lb = wv * 512;

    auto STAGE = [&](short* base, int koff) {
        gload16(g0 + koff, base + lb);
        gload16(g1 + koff, base + 2048 + lb);
        gload16(g2 + koff, base + 4096 + lb);
        gload16(g3 + koff, base + 6144 + lb);
        gload16(g4 + koff, base + 8192 + lb);
        gload16(g5 + koff, base + 10240 + lb);
        gload16(g6 + koff, base + 12288 + lb);
        gload16(g7 + koff, base + 14336 + lb);
    };

    f32x4 aX[2][2], aY[2][2];
    #pragma unroll
    for (int mt = 0; mt < 2; ++mt)
        #pragma unroll
        for (int nt = 0; nt < 2; ++nt) {
            aX[mt][nt] = (f32x4){0.f, 0.f, 0.f, 0.f};
            aY[mt][nt] = (f32x4){0.f, 0.f, 0.f, 0.f};
        }

    STAGE(sm, 0);

    #pragma unroll
    for (int ks = 0; ks < 4; ++ks) {
        short* cb = sm + (ks & 1) * 16384;
        if (ks < 3) {
            STAGE(sm + ((ks + 1) & 1) * 16384, (ks + 1) * 32);
            asm volatile("s_waitcnt vmcnt(8)" ::: "memory");
        } else {
            asm volatile("s_waitcnt vmcnt(0)" ::: "memory");
        }
        __builtin_amdgcn_s_barrier();
        __builtin_amdgcn_sched_barrier(0);

        bf16x8 xcH[2], xcL[2], xdH[2], xdL[2], ycH[2], ycL[2], ydH[2], ydL[2];
        #pragma unroll
        for (int mt = 0; mt < 2; ++mt) {
            int off = (wr * 32 + mt * 16 + (lane & 15)) * 32 + krd;
            xcH[mt] = *(const bf16x8*)(cb + off);
            xcL[mt] = *(const bf16x8*)(cb + 2048 + off);
            ycH[mt] = *(const bf16x8*)(cb + 8192 + off);
            ycL[mt] = *(const bf16x8*)(cb + 10240 + off);
        }
        #pragma unroll
        for (int nt = 0; nt < 2; ++nt) {
            int off = (wc * 32 + nt * 16 + (lane & 15)) * 32 + krd;
            xdH[nt] = *(const bf16x8*)(cb + 4096 + off);
            xdL[nt] = *(const bf16x8*)(cb + 6144 + off);
            ydH[nt] = *(const bf16x8*)(cb + 12288 + off);
            ydL[nt] = *(const bf16x8*)(cb + 14336 + off);
        }
        __builtin_amdgcn_s_setprio(1);
        #pragma unroll
        for (int mt = 0; mt < 2; ++mt)
            #pragma unroll
            for (int nt = 0; nt < 2; ++nt) {
                f32x4 cx = aX[mt][nt];
                cx = __builtin_amdgcn_mfma_f32_16x16x32_bf16(xcH[mt], xdH[nt], cx, 0, 0, 0);
                cx = __builtin_amdgcn_mfma_f32_16x16x32_bf16(xcH[mt], xdL[nt], cx, 0, 0, 0);
                cx = __builtin_amdgcn_mfma_f32_16x16x32_bf16(xcL[mt], xdH[nt], cx, 0, 0, 0);
                aX[mt][nt] = cx;
                f32x4 cy = aY[mt][nt];
                cy = __builtin_amdgcn_mfma_f32_16x16x32_bf16(ycH[mt], ydH[nt], cy, 0, 0, 0);
                cy = __builtin_amdgcn_mfma_f32_16x16x32_bf16(ycH[mt], ydL[nt], cy, 0, 0, 0);
                cy = __builtin_amdgcn_mfma_f32_16x16x32_bf16(ycL[mt], ydH[nt], cy, 0, 0, 0);
                aY[mt][nt] = cy;
            }
        __builtin_amdgcn_s_setprio(0);

        asm volatile("s_waitcnt lgkmcnt(0)" ::: "memory");
        __builtin_amdgcn_s_barrier();
        __builtin_amdgcn_sched_barrier(0);
    }

    // ---- coalesced epilogue: 64x64 diff tile via LDS (stride 68), float4 out ----
    float* fs = (float*)sm;                      // 64*68*4 = 17.4KB < 64KB
    #pragma unroll
    for (int mt = 0; mt < 2; ++mt) {
        int rl = wr * 32 + mt * 16 + ((lane >> 4) << 2);
        #pragma unroll
        for (int nt = 0; nt < 2; ++nt) {
            int cl = wc * 32 + nt * 16 + (lane & 15);
            #pragma unroll
            for (int r2 = 0; r2 < 4; ++r2)
                fs[(rl + r2) * 68 + cl] = aX[mt][nt][r2] - aY[mt][nt][r2];
        }
    }
    __syncthreads();
    float* Db = Dpart + ((size_t)sl * 10 + pr) * 4096;
    int rr0 = t >> 4;              // 0..15
    int cc0 = (t & 15) << 2;       // 0..60
    #pragma unroll
    for (int i = 0; i < 4; ++i) {
        int rr = rr0 + (i << 4);
        *(float4*)&Db[rr * 64 + cc0] = *(const float4*)&fs[rr * 68 + cc0];
    }
}

// ---------------- final loss (mask-sum fused; upper-tile iteration, off-diag x2) ----------------
__global__ void __launch_bounds__(256)
loss_kernel(const float* __restrict__ Dpart, const float* __restrict__ mask,
            float* __restrict__ out) {
    const int PI[10] = {0,0,0,0,1,1,1,2,2,3};
    const int PJ[10] = {0,1,2,3,1,2,3,2,3,3};
    __shared__ float red[4];
    int tid = threadIdx.x;

    float ms = 0.f;
    for (int i = tid; i < NPOS; i += 256) ms += mask[i];
    #pragma unroll
    for (int o = 32; o >= 1; o >>= 1) ms += __shfl_down(ms, o, 64);
    if ((tid & 63) == 0) red[tid >> 6] = ms;
    __syncthreads();
    float msum = 256.0f * (red[0] + red[1] + red[2] + red[3]);
    __syncthreads();                    // red[] reused below

    int e2 = blockIdx.x * 256 + tid;    // grid 160: 10 tiles x 4096
    int tt = e2 >> 12;                  // uniform within block
    int ei = e2 & 4095;
    float d = 0.f;
    #pragma unroll
    for (int s = 0; s < GSLICE; ++s)
        d += Dpart[(size_t)(s * 10 + tt) * 4096 + ei];
    float inv = 1.0f / msum;
    float v = d * inv;
    float w = (PI[tt] != PJ[tt]) ? 2.0f : 1.0f;
    float ls = w * v * v;
    #pragma unroll
    for (int o = 32; o >= 1; o >>= 1) ls += __shfl_down(ls, o, 64);
    if ((tid & 63) == 0) red[tid >> 6] = ls;
    __syncthreads();
    if (tid == 0)
        atomicAdd(out, (red[0] + red[1] + red[2] + red[3]) * (100.0f / 65536.0f));
}

extern "C" void kernel_launch(void* const* d_in, const int* in_sizes, int n_in,
                              void* d_out, int out_size, void* d_ws, size_t ws_size,
                              hipStream_t stream) {
    (void)in_sizes; (void)n_in; (void)out_size; (void)ws_size;
    const float* content = (const float*)d_in[0];
    const float* style   = (const float*)d_in[1];
    const float* input   = (const float*)d_in[2];
    const float* mask    = (const float*)d_in[3];
    float* out = (float*)d_out;

    auto alignup = [](size_t b) { return (b + 255) & ~size_t(255); };
    char* ws = (char*)d_ws;
    size_t off = 0;
    auto alloc = [&](size_t bytes) { void* p = ws + off; off += alignup(bytes); return p; };

    unsigned short* cTH = (unsigned short*)alloc((size_t)NPOS * C_CH * 2);
    unsigned short* cTL = (unsigned short*)alloc((size_t)NPOS * C_CH * 2);
    unsigned short* sTH = (unsigned short*)alloc((size_t)NPOS * C_CH * 2);
    unsigned short* sTL = (unsigned short*)alloc((size_t)NPOS * C_CH * 2);
    float* SSp   = (float*)alloc((size_t)8 * NPOS * 4);
    float* rs    = (float*)alloc((size_t)NPOS * 4);
    unsigned long long* PK = (unsigned long long*)alloc((size_t)NPOS * 8);
    unsigned short* XmH = (unsigned short*)alloc((size_t)C_CH * NPOS * 2);
    unsigned short* XmL = (unsigned short*)alloc((size_t)C_CH * NPOS * 2);
    unsigned short* YmH = (unsigned short*)alloc((size_t)C_CH * NPOS * 2);
    unsigned short* YmL = (unsigned short*)alloc((size_t)C_CH * NPOS * 2);
    float* Dpart = (float*)alloc((size_t)GSLICE * 10 * 4096 * 4);
    float* E     = (float*)alloc((size_t)NPOS * ENC * 4);

    split_kernel<<<dim3(64, 4, 3), 256, 0, stream>>>(content, style, cTH, cTL, sTH, sTL, SSp);

    int nwg = 1024;                      // (4096/128)^2, exact
    egemm_mfma<<<nwg, 512, 0, stream>>>(cTH, cTL, sTH, sTL, E, SSp, rs, PK, nwg);
    score_argmax<<<512, 256, 0, stream>>>(E, rs, PK);
    build_xy_kernel<<<1024, 256, 0, stream>>>(input, style, mask, PK, XmH, XmL, YmH, YmL, out);
    gram_mfma<<<dim3(10, GSLICE), 256, 0, stream>>>(XmH, XmL, YmH, YmL, Dpart);
    loss_kernel<<<160, 256, 0, stream>>>(Dpart, mask, out);
}